// Round 7
// baseline (307.592 us; speedup 1.0000x reference)
//
#include <hip/hip_runtime.h>

// Problem constants (match reference file)
#define B_   2
#define S_   2048
#define D_   512
#define H_   8
#define DK_  64
#define FF_  2048
#define EPS_ 1e-3f
#define QS_  1536   // fused QKV row stride

typedef __bf16 bf16;
typedef __bf16 bf16x4 __attribute__((ext_vector_type(4)));
typedef __bf16 bf16x8 __attribute__((ext_vector_type(8)));
typedef float  f32x4  __attribute__((ext_vector_type(4)));

// ---------------------------------------------------------------------------
// Weight transpose + hi/lo bf16 split:  W[K][N] -> T{hi,lo}[rowOff+n][k]
// ---------------------------------------------------------------------------
struct Trans4Args {
  const float* w[4];
  bf16* thi[4];
  bf16* tlo[4];
  int rowOff[4];
};

__global__ __launch_bounds__(256) void transpose4_kernel(Trans4Args a) {
  __shared__ float tl[32][33];
  const int t = threadIdx.x;
  const int tx = t & 31, ty = t >> 5;  // 32 x 8
  const int n0 = blockIdx.x * 32, k0 = blockIdx.y * 32;
  const int wsel = blockIdx.z;
  const float* __restrict__ W = a.w[wsel];
#pragma unroll
  for (int r = 0; r < 32; r += 8)
    tl[r + ty][tx] = W[(size_t)(k0 + r + ty) * 512 + n0 + tx];
  __syncthreads();
  bf16* __restrict__ Thi = a.thi[wsel];
  bf16* __restrict__ Tlo = a.tlo[wsel];
  const int ro = a.rowOff[wsel];
#pragma unroll
  for (int r = 0; r < 32; r += 8) {
    const int n = r + ty;
    const float v = tl[tx][n];  // stride-33 -> conflict-free
    const bf16 h = (bf16)v;
    const size_t o = (size_t)(ro + n0 + n) * 512 + k0 + tx;
    Thi[o] = h;
    Tlo[o] = (bf16)(v - (float)h);
  }
}

__global__ __launch_bounds__(256) void transpose_split_kernel(
    const float* __restrict__ W, int K, int N,
    bf16* __restrict__ Thi, bf16* __restrict__ Tlo) {
  __shared__ float tl[32][33];
  const int t = threadIdx.x;
  const int tx = t & 31, ty = t >> 5;
  const int n0 = blockIdx.x * 32, k0 = blockIdx.y * 32;
#pragma unroll
  for (int r = 0; r < 32; r += 8)
    tl[r + ty][tx] = W[(size_t)(k0 + r + ty) * N + n0 + tx];
  __syncthreads();
#pragma unroll
  for (int r = 0; r < 32; r += 8) {
    const int n = r + ty;
    const float v = tl[tx][n];
    const bf16 h = (bf16)v;
    const size_t o = (size_t)(n0 + n) * K + k0 + tx;
    Thi[o] = h;
    Tlo[o] = (bf16)(v - (float)h);
  }
}

__global__ __launch_bounds__(256) void pack_bias_kernel(const float* __restrict__ bq,
                                                        const float* __restrict__ bk,
                                                        const float* __restrict__ bv,
                                                        float* __restrict__ out) {
  const int i = blockIdx.x * 256 + threadIdx.x;  // 0..1535
  out[i] = (i < 512) ? bq[i] : (i < 1024) ? bk[i - 512] : bv[i - 1024];
}

// ---------------------------------------------------------------------------
// Pad-mask + hi/lo split
// ---------------------------------------------------------------------------
__global__ __launch_bounds__(256) void mask_split_kernel(const float* __restrict__ x,
                                                         const int* __restrict__ lengths,
                                                         bf16* __restrict__ xhi,
                                                         bf16* __restrict__ xlo) {
  const int idx = blockIdx.x * 256 + threadIdx.x;
  const int d4 = D_ / 4;
  const int s = (idx / d4) & (S_ - 1);
  const int b = idx / (d4 * S_);
  float4 v = reinterpret_cast<const float4*>(x)[idx];
  if (s >= lengths[b]) { v.x = 0.f; v.y = 0.f; v.z = 0.f; v.w = 0.f; }
  const float vv[4] = {v.x, v.y, v.z, v.w};
  bf16x4 h, l;
#pragma unroll
  for (int c = 0; c < 4; ++c) {
    const bf16 hh = (bf16)vv[c];
    h[c] = hh;
    l[c] = (bf16)(vv[c] - (float)hh);
  }
  reinterpret_cast<bf16x4*>(xhi)[idx] = h;
  reinterpret_cast<bf16x4*>(xlo)[idx] = l;
}

// ---------------------------------------------------------------------------
// Split-bf16 MFMA GEMM, 64x64 tile, BK=32, 256 thr = 4 waves (2x2), each wave
// 32x32 (2x2 frags). 3 MFMA products per acc (hi*hi + hi*lo + lo*hi).
// Split-K: grid = 8-XCD-swizzled 1D over (split, m, n); partial s writes to
// (s ? C2 : C) with NO bias (EPI_PART); downstream LN sums partials.
// ---------------------------------------------------------------------------
enum { EPI_BIAS = 0, EPI_BIAS_RELU = 2, EPI_PART = 4 };

template <int EPI, bool SPLIT>
__global__ __launch_bounds__(256) void gemm_kernel(
    const bf16* __restrict__ Ahi, const bf16* __restrict__ Alo,
    const bf16* __restrict__ Bhi, const bf16* __restrict__ Blo,
    const float* __restrict__ bias,
    float* __restrict__ C, float* __restrict__ C2,
    bf16* __restrict__ Chi, bf16* __restrict__ Clo,
    int K, int ldc, int nx, int mn, int ksplit) {
  // rows padded to 40 bf16 (80 B = 5x16B): 16B-aligned, spread over banks
  __shared__ __align__(16) bf16 As[2][64][40];
  __shared__ __align__(16) bf16 Bs[2][64][40];
  const int t = threadIdx.x;

  const int nwg = gridDim.x;
  const int chunk = nwg >> 3;
  const int virt = (blockIdx.x & 7) * chunk + (blockIdx.x >> 3);
  const int s = virt / mn;
  const int v2 = virt - s * mn;
  const int m0 = (v2 / nx) * 64, n0 = (v2 % nx) * 64;
  const int kb = s * ksplit;

  const int ar = t >> 2, ak = (t & 3) * 8;  // staging: row 0..63, 16B chunk
  const int lane = t & 63, wv = t >> 6;
  const int wm = (wv >> 1) * 32, wn = (wv & 1) * 32;
  const int fr = lane & 15, fg = lane >> 4;

  f32x4 acc[2][2] = {};

  const bf16* pAhi = Ahi + (size_t)(m0 + ar) * K + kb + ak;
  const bf16* pAlo = Alo + (size_t)(m0 + ar) * K + kb + ak;
  const bf16* pBhi = Bhi + (size_t)(n0 + ar) * K + kb + ak;
  const bf16* pBlo = Blo + (size_t)(n0 + ar) * K + kb + ak;

  for (int k0 = 0; k0 < ksplit; k0 += 32) {
    *reinterpret_cast<int4*>(&As[0][ar][ak]) = *reinterpret_cast<const int4*>(pAhi + k0);
    *reinterpret_cast<int4*>(&As[1][ar][ak]) = *reinterpret_cast<const int4*>(pAlo + k0);
    *reinterpret_cast<int4*>(&Bs[0][ar][ak]) = *reinterpret_cast<const int4*>(pBhi + k0);
    *reinterpret_cast<int4*>(&Bs[1][ar][ak]) = *reinterpret_cast<const int4*>(pBlo + k0);
    __syncthreads();

    bf16x8 ah[2], al[2], bh[2], bl[2];
#pragma unroll
    for (int m = 0; m < 2; ++m) {
      ah[m] = *reinterpret_cast<const bf16x8*>(&As[0][wm + m * 16 + fr][fg * 8]);
      al[m] = *reinterpret_cast<const bf16x8*>(&As[1][wm + m * 16 + fr][fg * 8]);
      bh[m] = *reinterpret_cast<const bf16x8*>(&Bs[0][wn + m * 16 + fr][fg * 8]);
      bl[m] = *reinterpret_cast<const bf16x8*>(&Bs[1][wn + m * 16 + fr][fg * 8]);
    }
#pragma unroll
    for (int m = 0; m < 2; ++m)
#pragma unroll
      for (int n = 0; n < 2; ++n) {
        acc[m][n] = __builtin_amdgcn_mfma_f32_16x16x32_bf16(ah[m], bh[n], acc[m][n], 0, 0, 0);
        acc[m][n] = __builtin_amdgcn_mfma_f32_16x16x32_bf16(ah[m], bl[n], acc[m][n], 0, 0, 0);
        acc[m][n] = __builtin_amdgcn_mfma_f32_16x16x32_bf16(al[m], bh[n], acc[m][n], 0, 0, 0);
      }
    __syncthreads();
  }

  float* __restrict__ Cw = (s == 0) ? C : C2;
  float bcol[2] = {0.f, 0.f};
  if constexpr (EPI != EPI_PART) {
#pragma unroll
    for (int n = 0; n < 2; ++n) bcol[n] = bias[n0 + wn + n * 16 + fr];
  }
#pragma unroll
  for (int m = 0; m < 2; ++m)
#pragma unroll
    for (int n = 0; n < 2; ++n) {
      const int col = n0 + wn + n * 16 + fr;
#pragma unroll
      for (int r = 0; r < 4; ++r) {
        const int row = m0 + wm + m * 16 + fg * 4 + r;
        float v = acc[m][n][r] + bcol[n];
        if constexpr (EPI == EPI_BIAS_RELU) v = fmaxf(v, 0.f);
        const size_t o = (size_t)row * ldc + col;
        if constexpr (SPLIT) {
          const bf16 h = (bf16)v;
          Chi[o] = h;
          Clo[o] = (bf16)(v - (float)h);
        } else {
          Cw[o] = v;
        }
      }
    }
}

// ---------------------------------------------------------------------------
// Attention phase 1: one block per causal (i-tile64, j-chunk128) pair x (b,h).
// Per-row partial online-softmax stats (m, l, d) over <=2 k-tiles.
// ---------------------------------------------------------------------------
__global__ __launch_bounds__(256) void attn_part_kernel(const float* __restrict__ qkv,
                                                        const int* __restrict__ lengths,
                                                        float* __restrict__ pm,
                                                        float* __restrict__ pl,
                                                        float* __restrict__ pd) {
  __shared__ __align__(16) float Qs[64][68];
  __shared__ __align__(16) float Ks[64][68];
  const int t = threadIdx.x;
  const int tx = t & 15, ty = t >> 4;
  const int bh = blockIdx.y;
  const int bb = bh >> 3, h = bh & 7;

  // unflatten p -> (ib, jc): ib=2a starts at a^2+a, ib=2a+1 starts at (a+1)^2
  const int p = blockIdx.x;
  int a = (int)sqrtf((float)p);
  while ((a + 1) * (a + 1) <= p) ++a;
  while (a * a > p) --a;
  int ib, jc;
  if (p >= a * a + a) { ib = 2 * a;     jc = p - (a * a + a); }
  else                { ib = 2 * a - 1; jc = p - a * a; }

  const int i0 = ib * 64;
  const int len = lengths[bb];
  if (i0 >= len || jc * 128 >= len) return;  // block-uniform: partials unread

  {  // stage Q tile
    const int r_ = t >> 4, quad = t & 15;
#pragma unroll
    for (int it = 0; it < 4; ++it) {
      const int r = it * 16 + r_;
      *reinterpret_cast<float4*>(&Qs[r][quad * 4]) = *reinterpret_cast<const float4*>(
          qkv + (size_t)(bb * S_ + i0 + r) * QS_ + h * DK_ + quad * 4);
    }
  }

  float m_r[4], l_r[4], d_r[4];
#pragma unroll
  for (int ii = 0; ii < 4; ++ii) { m_r[ii] = -1e30f; l_r[ii] = 0.f; d_r[ii] = 0.f; }

  const int jlim = min(i0 + 63, len - 1);
  for (int jt = 0; jt < 2; ++jt) {
    const int j0 = jc * 128 + jt * 64;
    if (j0 > jlim) break;  // uniform
    {  // stage K tile
      const int r_ = t >> 4, quad = t & 15;
#pragma unroll
      for (int it = 0; it < 4; ++it) {
        const int r = it * 16 + r_;
        *reinterpret_cast<float4*>(&Ks[r][quad * 4]) = *reinterpret_cast<const float4*>(
            qkv + (size_t)(bb * S_ + j0 + r) * QS_ + D_ + h * DK_ + quad * 4);
      }
    }
    __syncthreads();

    float sc[4][4] = {};
#pragma unroll 4
    for (int d0 = 0; d0 < 64; d0 += 4) {
      float4 qv[4], kv[4];
#pragma unroll
      for (int ii = 0; ii < 4; ++ii) qv[ii] = *reinterpret_cast<const float4*>(&Qs[ii * 16 + ty][d0]);
#pragma unroll
      for (int jj = 0; jj < 4; ++jj) kv[jj] = *reinterpret_cast<const float4*>(&Ks[jj * 16 + tx][d0]);
#pragma unroll
      for (int ii = 0; ii < 4; ++ii)
#pragma unroll
        for (int jj = 0; jj < 4; ++jj) {
          sc[ii][jj] = fmaf(qv[ii].x, kv[jj].x, sc[ii][jj]);
          sc[ii][jj] = fmaf(qv[ii].y, kv[jj].y, sc[ii][jj]);
          sc[ii][jj] = fmaf(qv[ii].z, kv[jj].z, sc[ii][jj]);
          sc[ii][jj] = fmaf(qv[ii].w, kv[jj].w, sc[ii][jj]);
        }
    }

#pragma unroll
    for (int ii = 0; ii < 4; ++ii) {
      const int ig = i0 + ii * 16 + ty;
      float mx = -1e30f;
#pragma unroll
      for (int jj = 0; jj < 4; ++jj) {
        const int j = j0 + jj * 16 + tx;
        if (j > ig || j >= len) sc[ii][jj] = -1e30f;
        mx = fmaxf(mx, sc[ii][jj]);
      }
#pragma unroll
      for (int off = 1; off < 16; off <<= 1) mx = fmaxf(mx, __shfl_xor(mx, off));
      const float mnew = fmaxf(m_r[ii], mx);
      float ps = 0.f, pdg = 0.f;
#pragma unroll
      for (int jj = 0; jj < 4; ++jj) {
        const int j = j0 + jj * 16 + tx;
        const float e = __expf(sc[ii][jj] - mnew);
        ps += e;
        if (j == ig) pdg = e;
      }
#pragma unroll
      for (int off = 1; off < 16; off <<= 1) {
        ps += __shfl_xor(ps, off);
        pdg += __shfl_xor(pdg, off);
      }
      const float scale = __expf(m_r[ii] - mnew);
      l_r[ii] = l_r[ii] * scale + ps;
      d_r[ii] = d_r[ii] * scale + pdg;
      m_r[ii] = mnew;
    }
    __syncthreads();
  }

  if (tx == 0) {  // write partials (one lane per row)
    const size_t base = ((size_t)(bh * 32 + ib) * 16 + jc) * 64;
#pragma unroll
    for (int ii = 0; ii < 4; ++ii) {
      const int row = ii * 16 + ty;
      const float mm = m_r[ii];
      const bool ok = mm > -1e29f;  // row saw >=1 valid key in this chunk
      pm[base + row] = mm;
      pl[base + row] = ok ? l_r[ii] : 0.f;
      pd[base + row] = ok ? d_r[ii] : 0.f;
    }
  }
}

// ---------------------------------------------------------------------------
// Attention phase 2: merge partials per (b,h,i-tile), write wgt=(d/l)*v bf16
// ---------------------------------------------------------------------------
__global__ __launch_bounds__(256) void attn_merge_kernel(
    const float* __restrict__ qkv, const int* __restrict__ lengths,
    const float* __restrict__ pm, const float* __restrict__ pl,
    const float* __restrict__ pd, bf16* __restrict__ whi, bf16* __restrict__ wlo) {
  __shared__ float msh[4][64], lsh[4][64], dsh[4][64];
  __shared__ float dgs[64];
  const int t = threadIdx.x;
  const int ib = blockIdx.x, bh = blockIdx.y;
  const int bb = bh >> 3, h = bh & 7;
  const int i0 = ib * 64;
  const int len = lengths[bb];

  const int r = t & 63, g = t >> 6;
  float m = -1e30f, l = 0.f, d = 0.f;
  if (i0 < len) {  // else partials unread (poison-safe: dg forced 0 below)
    const int jcmax = min((i0 + 63) >> 7, (len - 1) >> 7);
    const size_t base = ((size_t)(bh * 32 + ib) * 16) * 64 + r;
    for (int jc = g; jc <= jcmax; jc += 4) {
      const size_t idx = base + (size_t)jc * 64;
      const float m2 = pm[idx], l2 = pl[idx], d2 = pd[idx];
      const float mn = fmaxf(m, m2);
      const float e1 = __expf(m - mn), e2 = __expf(m2 - mn);
      l = l * e1 + l2 * e2;
      d = d * e1 + d2 * e2;
      m = mn;
    }
  }
  msh[g][r] = m; lsh[g][r] = l; dsh[g][r] = d;
  __syncthreads();
  if (t < 64) {
    float M = msh[0][t], L = lsh[0][t], Dv = dsh[0][t];
#pragma unroll
    for (int gg = 1; gg < 4; ++gg) {
      const float m2 = msh[gg][t], l2 = lsh[gg][t], d2 = dsh[gg][t];
      const float mn = fmaxf(M, m2);
      const float e1 = __expf(M - mn), e2 = __expf(m2 - mn);
      L = L * e1 + l2 * e2;
      Dv = Dv * e1 + d2 * e2;
      M = mn;
    }
    // valid rows always have the jc=0 partial with l >= 1 -> L >= 1
    dgs[t] = (i0 + t < len) ? Dv / L : 0.f;
  }
  __syncthreads();

  const int rr = t >> 2, q = t & 3;
  const float dg = dgs[rr];
  const size_t vbase = (size_t)(bb * S_ + i0 + rr) * QS_ + 2 * D_ + h * DK_;
  const size_t obase = (size_t)(bb * S_ + i0 + rr) * D_ + h * DK_;
#pragma unroll
  for (int kk = 0; kk < 4; ++kk) {
    const int col = q * 4 + kk * 16;
    const float4 v4 = *reinterpret_cast<const float4*>(qkv + vbase + col);
    const float vv[4] = {dg * v4.x, dg * v4.y, dg * v4.z, dg * v4.w};
    bf16x4 hh, ll;
#pragma unroll
    for (int c = 0; c < 4; ++c) {
      const bf16 x = (bf16)vv[c];
      hh[c] = x;
      ll[c] = (bf16)(vv[c] - (float)x);
    }
    *reinterpret_cast<bf16x4*>(&whi[obase + col]) = hh;
    *reinterpret_cast<bf16x4*>(&wlo[obase + col]) = ll;
  }
}

// ---------------------------------------------------------------------------
// LN1 fused: h1 = P0 + P1 + bo + mask(x); y1 = LN(h1) written as bf16 hi/lo.
// One block per row.
// ---------------------------------------------------------------------------
__global__ __launch_bounds__(256) void ln1_fused_kernel(
    const float* __restrict__ P0, const float* __restrict__ P1,
    const float* __restrict__ x, const int* __restrict__ lengths,
    const float* __restrict__ bo,
    const float* __restrict__ gamma, const float* __restrict__ beta,
    bf16* __restrict__ Yhi, bf16* __restrict__ Ylo) {
  const int row = blockIdx.x;
  const int t = threadIdx.x;
  const int lenb = lengths[row >> 11];
  const bool valid = (row & (S_ - 1)) < lenb;
  const size_t ro = (size_t)row * D_ + t * 2;
  const float2 p0 = *reinterpret_cast<const float2*>(P0 + ro);
  const float2 p1 = *reinterpret_cast<const float2*>(P1 + ro);
  const float2 xv = *reinterpret_cast<const float2*>(x + ro);
  const float2 bv = *reinterpret_cast<const float2*>(bo + t * 2);
  float hx = p0.x + p1.x + bv.x + (valid ? xv.x : 0.f);
  float hy = p0.y + p1.y + bv.y + (valid ? xv.y : 0.f);

  float s = hx + hy, s2 = hx * hx + hy * hy;
#pragma unroll
  for (int off = 1; off < 64; off <<= 1) {
    s += __shfl_xor(s, off);
    s2 += __shfl_xor(s2, off);
  }
  __shared__ float red[8];
  const int w = t >> 6;
  if ((t & 63) == 0) { red[w] = s; red[4 + w] = s2; }
  __syncthreads();
  const float ts  = red[0] + red[1] + red[2] + red[3];
  const float ts2 = red[4] + red[5] + red[6] + red[7];
  const float mean = ts * (1.f / D_);
  const float var  = ts2 * (1.f / D_) - mean * mean;
  const float inv  = 1.f / sqrtf(var + EPS_);
  const float2 g  = *reinterpret_cast<const float2*>(gamma + t * 2);
  const float2 bt = *reinterpret_cast<const float2*>(beta + t * 2);
  const float ox = g.x * ((hx - mean) * inv) + bt.x;
  const float oy = g.y * ((hy - mean) * inv) + bt.y;
  const bf16 ohx = (bf16)ox, ohy = (bf16)oy;
  Yhi[ro] = ohx;  Yhi[ro + 1] = ohy;
  Ylo[ro] = (bf16)(ox - (float)ohx);
  Ylo[ro + 1] = (bf16)(oy - (float)ohy);
}

// ---------------------------------------------------------------------------
// LN2 fused: h2 = Q0 + Q1 + b2 + (y1hi+y1lo); out = LN(h2) f32.
// ---------------------------------------------------------------------------
__global__ __launch_bounds__(256) void ln2_fused_kernel(
    const float* __restrict__ Q0, const float* __restrict__ Q1,
    const bf16* __restrict__ Yhi, const bf16* __restrict__ Ylo,
    const float* __restrict__ b2,
    const float* __restrict__ gamma, const float* __restrict__ beta,
    float* __restrict__ out) {
  const int row = blockIdx.x;
  const int t = threadIdx.x;
  const size_t ro = (size_t)row * D_ + t * 2;
  const float2 q0 = *reinterpret_cast<const float2*>(Q0 + ro);
  const float2 q1 = *reinterpret_cast<const float2*>(Q1 + ro);
  const float2 bv = *reinterpret_cast<const float2*>(b2 + t * 2);
  const float y1x = (float)Yhi[ro] + (float)Ylo[ro];
  const float y1y = (float)Yhi[ro + 1] + (float)Ylo[ro + 1];
  float hx = q0.x + q1.x + bv.x + y1x;
  float hy = q0.y + q1.y + bv.y + y1y;

  float s = hx + hy, s2 = hx * hx + hy * hy;
#pragma unroll
  for (int off = 1; off < 64; off <<= 1) {
    s += __shfl_xor(s, off);
    s2 += __shfl_xor(s2, off);
  }
  __shared__ float red[8];
  const int w = t >> 6;
  if ((t & 63) == 0) { red[w] = s; red[4 + w] = s2; }
  __syncthreads();
  const float ts  = red[0] + red[1] + red[2] + red[3];
  const float ts2 = red[4] + red[5] + red[6] + red[7];
  const float mean = ts * (1.f / D_);
  const float var  = ts2 * (1.f / D_) - mean * mean;
  const float inv  = 1.f / sqrtf(var + EPS_);
  const float2 g  = *reinterpret_cast<const float2*>(gamma + t * 2);
  const float2 bt = *reinterpret_cast<const float2*>(beta + t * 2);
  float2 o;
  o.x = g.x * ((hx - mean) * inv) + bt.x;
  o.y = g.y * ((hy - mean) * inv) + bt.y;
  *reinterpret_cast<float2*>(out + ro) = o;
}

// ---------------------------------------------------------------------------
extern "C" void kernel_launch(void* const* d_in, const int* in_sizes, int n_in,
                              void* d_out, int out_size, void* d_ws, size_t ws_size,
                              hipStream_t stream) {
  const float* x       = (const float*)d_in[0];
  const int*   lengths = (const int*)d_in[1];
  const float* Wq = (const float*)d_in[2];
  const float* bq = (const float*)d_in[3];
  const float* Wk = (const float*)d_in[4];
  const float* bk = (const float*)d_in[5];
  const float* Wv = (const float*)d_in[6];
  const float* bv = (const float*)d_in[7];
  const float* Wo = (const float*)d_in[8];
  const float* bo = (const float*)d_in[9];
  const float* W1 = (const float*)d_in[10];
  const float* b1 = (const float*)d_in[11];
  const float* W2 = (const float*)d_in[12];
  const float* b2 = (const float*)d_in[13];
  const float* gamma1 = (const float*)d_in[14];
  const float* beta1  = (const float*)d_in[15];
  const float* gamma2 = (const float*)d_in[16];
  const float* beta2  = (const float*)d_in[17];
  float* out = (float*)d_out;

  char* ws = (char*)d_ws;
  // ---- workspace layout (lifetime-overlapped, < 64 MB) ----
  // weights (live until their GEMM completes):
  bf16*  qkvT_hi = (bf16*)(ws + 0);          // [1536][512]
  bf16*  qkvT_lo = (bf16*)(ws + 1572864);
  bf16*  WoT_hi  = (bf16*)(ws + 3145728);    // [512][512]
  bf16*  WoT_lo  = (bf16*)(ws + 3670016);
  bf16*  W1T_hi  = (bf16*)(ws + 4194304);    // [2048][512]
  bf16*  W1T_lo  = (bf16*)(ws + 6291456);
  bf16*  W2T_hi  = (bf16*)(ws + 8388608);    // [512][2048]
  bf16*  W2T_lo  = (bf16*)(ws + 10485760);
  float* bqkv    = (float*)(ws + 12582912);  // [1536]
  // region A: qkv f32 (25.2MB) -> Wo partials P0/P1 -> ff1 hi/lo (33.5MB)
  float* qkv_f32 = (float*)(ws + 12589056);  // [4096][1536]
  float* P0      = (float*)(ws + 12589056);  // [4096][512] (after attn)
  float* P1      = (float*)(ws + 20977664);
  float* part_m  = (float*)(ws + 37754880);  // attn partials, 6MB window
  float* part_l  = (float*)(ws + 39852032);
  float* part_d  = (float*)(ws + 41949184);  // ends 44046336
  bf16*  ff1_hi  = (bf16*)(ws + 12589056);   // [4096][2048] (after LN1)
  bf16*  ff1_lo  = (bf16*)(ws + 29366272);   // ends 46143488
  // region B: xm hi/lo -> y1 hi/lo (live through LN2)
  bf16*  xm_hi   = (bf16*)(ws + 46143488);   // [4096][512]
  bf16*  xm_lo   = (bf16*)(ws + 50337792);
  bf16*  y1_hi   = (bf16*)(ws + 46143488);
  bf16*  y1_lo   = (bf16*)(ws + 50337792);
  // region C: wgt hi/lo -> FF2 partial Q0
  bf16*  wgt_hi  = (bf16*)(ws + 54532096);   // [4096][512]
  bf16*  wgt_lo  = (bf16*)(ws + 58726400);   // ends 62920704
  float* Q0      = (float*)(ws + 54532096);  // (after Wo)
  // FF2 partial Q1 over dead qkvT/WoT/W1T weights (after FF1):
  float* Q1      = (float*)(ws + 0);         // [4096][512] = 8.4MB, ends 8388608

  const dim3 blk(256);
  const int M = B_ * S_;  // 4096

  // 1) weight transposes + hi/lo splits
  Trans4Args ta;
  ta.w[0] = Wq; ta.w[1] = Wk; ta.w[2] = Wv; ta.w[3] = Wo;
  ta.thi[0] = qkvT_hi; ta.thi[1] = qkvT_hi; ta.thi[2] = qkvT_hi; ta.thi[3] = WoT_hi;
  ta.tlo[0] = qkvT_lo; ta.tlo[1] = qkvT_lo; ta.tlo[2] = qkvT_lo; ta.tlo[3] = WoT_lo;
  ta.rowOff[0] = 0; ta.rowOff[1] = 512; ta.rowOff[2] = 1024; ta.rowOff[3] = 0;
  transpose4_kernel<<<dim3(16, 16, 4), blk, 0, stream>>>(ta);
  transpose_split_kernel<<<dim3(64, 16), blk, 0, stream>>>(W1, 512, 2048, W1T_hi, W1T_lo);
  transpose_split_kernel<<<dim3(16, 64), blk, 0, stream>>>(W2, 2048, 512, W2T_hi, W2T_lo);
  pack_bias_kernel<<<dim3(6), blk, 0, stream>>>(bq, bk, bv, bqkv);

  // 2) mask + split
  mask_split_kernel<<<dim3((M * D_ / 4) / 256), blk, 0, stream>>>(x, lengths, xm_hi, xm_lo);

  // 3) fused QKV GEMM -> qkv_f32.  grid 64x24 = 1536 (%8==0)
  gemm_kernel<EPI_BIAS, false><<<dim3(1536), blk, 0, stream>>>(
      xm_hi, xm_lo, qkvT_hi, qkvT_lo, bqkv,
      qkv_f32, nullptr, nullptr, nullptr, 512, QS_, 24, 1536, 512);

  // 4) attention: balanced partials (272 causal pairs x 16 bh) + merge
  attn_part_kernel<<<dim3(272, 16), blk, 0, stream>>>(qkv_f32, lengths, part_m, part_l, part_d);
  attn_merge_kernel<<<dim3(32, 16), blk, 0, stream>>>(qkv_f32, lengths, part_m, part_l, part_d,
                                                      wgt_hi, wgt_lo);

  // 5) O-proj split-K=2 partials.  grid 2x64x8 = 1024
  gemm_kernel<EPI_PART, false><<<dim3(1024), blk, 0, stream>>>(
      wgt_hi, wgt_lo, WoT_hi, WoT_lo, nullptr,
      P0, P1, nullptr, nullptr, 512, D_, 8, 512, 256);

  // 6) LN1 fused (P0+P1+bo+mask(x)) -> y1 hi/lo
  ln1_fused_kernel<<<dim3(M), blk, 0, stream>>>(P0, P1, x, lengths, bo,
                                                gamma1, beta1, y1_hi, y1_lo);

  // 7) FF1 (+bias+relu) -> ff1 hi/lo.  grid 64x32 = 2048
  gemm_kernel<EPI_BIAS_RELU, true><<<dim3(2048), blk, 0, stream>>>(
      y1_hi, y1_lo, W1T_hi, W1T_lo, b1,
      nullptr, nullptr, ff1_hi, ff1_lo, 512, FF_, 32, 2048, 512);

  // 8) FF2 split-K=2 partials.  grid 2x64x8 = 1024
  gemm_kernel<EPI_PART, false><<<dim3(1024), blk, 0, stream>>>(
      ff1_hi, ff1_lo, W2T_hi, W2T_lo, nullptr,
      Q0, Q1, nullptr, nullptr, FF_, D_, 8, 512, 1024);

  // 9) LN2 fused (Q0+Q1+b2+y1) -> out
  ln2_fused_kernel<<<dim3(M), blk, 0, stream>>>(Q0, Q1, y1_hi, y1_lo, b2,
                                                gamma2, beta2, out);
}

// Round 8
// 286.193 us; speedup vs baseline: 1.0748x; 1.0748x over previous
//
#include <hip/hip_runtime.h>

// Problem constants (match reference file)
#define B_   2
#define S_   2048
#define D_   512
#define H_   8
#define DK_  64
#define FF_  2048
#define EPS_ 1e-3f
#define QS_  1536   // fused QKV output width (q|k|v)

typedef __bf16 bf16;
typedef __bf16 bf16x4 __attribute__((ext_vector_type(4)));
typedef __bf16 bf16x8 __attribute__((ext_vector_type(8)));
typedef float  f32x4  __attribute__((ext_vector_type(4)));

// ---------------------------------------------------------------------------
// Weight transpose + hi/lo bf16 split:  W[K][N] -> T{hi,lo}[rowOff+n][k]
// ---------------------------------------------------------------------------
struct Trans4Args {
  const float* w[4];
  bf16* thi[4];
  bf16* tlo[4];
  int rowOff[4];
};

__global__ __launch_bounds__(256) void transpose4_kernel(Trans4Args a) {
  __shared__ float tl[32][33];
  const int t = threadIdx.x;
  const int tx = t & 31, ty = t >> 5;  // 32 x 8
  const int n0 = blockIdx.x * 32, k0 = blockIdx.y * 32;
  const int wsel = blockIdx.z;
  const float* __restrict__ W = a.w[wsel];
#pragma unroll
  for (int r = 0; r < 32; r += 8)
    tl[r + ty][tx] = W[(size_t)(k0 + r + ty) * 512 + n0 + tx];
  __syncthreads();
  bf16* __restrict__ Thi = a.thi[wsel];
  bf16* __restrict__ Tlo = a.tlo[wsel];
  const int ro = a.rowOff[wsel];
#pragma unroll
  for (int r = 0; r < 32; r += 8) {
    const int n = r + ty;
    const float v = tl[tx][n];  // stride-33 -> conflict-free
    const bf16 h = (bf16)v;
    const size_t o = (size_t)(ro + n0 + n) * 512 + k0 + tx;
    Thi[o] = h;
    Tlo[o] = (bf16)(v - (float)h);
  }
}

__global__ __launch_bounds__(256) void transpose_split_kernel(
    const float* __restrict__ W, int K, int N,
    bf16* __restrict__ Thi, bf16* __restrict__ Tlo) {
  __shared__ float tl[32][33];
  const int t = threadIdx.x;
  const int tx = t & 31, ty = t >> 5;
  const int n0 = blockIdx.x * 32, k0 = blockIdx.y * 32;
#pragma unroll
  for (int r = 0; r < 32; r += 8)
    tl[r + ty][tx] = W[(size_t)(k0 + r + ty) * N + n0 + tx];
  __syncthreads();
#pragma unroll
  for (int r = 0; r < 32; r += 8) {
    const int n = r + ty;
    const float v = tl[tx][n];
    const bf16 h = (bf16)v;
    const size_t o = (size_t)(n0 + n) * K + k0 + tx;
    Thi[o] = h;
    Tlo[o] = (bf16)(v - (float)h);
  }
}

__global__ __launch_bounds__(256) void pack_bias_kernel(const float* __restrict__ bq,
                                                        const float* __restrict__ bk,
                                                        const float* __restrict__ bv,
                                                        float* __restrict__ out) {
  const int i = blockIdx.x * 256 + threadIdx.x;  // 0..1535
  out[i] = (i < 512) ? bq[i] : (i < 1024) ? bk[i - 512] : bv[i - 1024];
}

// ---------------------------------------------------------------------------
// Pad-mask + hi/lo split
// ---------------------------------------------------------------------------
__global__ __launch_bounds__(256) void mask_split_kernel(const float* __restrict__ x,
                                                         const int* __restrict__ lengths,
                                                         bf16* __restrict__ xhi,
                                                         bf16* __restrict__ xlo) {
  const int idx = blockIdx.x * 256 + threadIdx.x;
  const int d4 = D_ / 4;
  const int s = (idx / d4) & (S_ - 1);
  const int b = idx / (d4 * S_);
  float4 v = reinterpret_cast<const float4*>(x)[idx];
  if (s >= lengths[b]) { v.x = 0.f; v.y = 0.f; v.z = 0.f; v.w = 0.f; }
  const float vv[4] = {v.x, v.y, v.z, v.w};
  bf16x4 h, l;
#pragma unroll
  for (int c = 0; c < 4; ++c) {
    const bf16 hh = (bf16)vv[c];
    h[c] = hh;
    l[c] = (bf16)(vv[c] - (float)hh);
  }
  reinterpret_cast<bf16x4*>(xhi)[idx] = h;
  reinterpret_cast<bf16x4*>(xlo)[idx] = l;
}

// ---------------------------------------------------------------------------
// Split-bf16 MFMA GEMM, 64x64 tile, BK=32, 256 thr = 4 waves (2x2).
// OPERAND-SWAPPED: we compute C^T fragments (mfma(B,A)), so lane l holds
// C[row = m-tile + (l&15)][cols n-tile + (l>>4)*4 .. +3] -> float4/bf16x4
// vector stores (64B-coalesced across the 4 fg lane-groups).
// Split-K: partial s=1 writes to C2 (no bias); downstream LN sums partials.
// ---------------------------------------------------------------------------
enum { EPI_BIAS_RELU = 2, EPI_PART = 4, EPI_QKV = 5 };

template <int EPI, bool SPLIT>
__global__ __launch_bounds__(256) void gemm_kernel(
    const bf16* __restrict__ Ahi, const bf16* __restrict__ Alo,
    const bf16* __restrict__ Bhi, const bf16* __restrict__ Blo,
    const float* __restrict__ bias,
    float* __restrict__ C, float* __restrict__ C2,
    bf16* __restrict__ Chi, bf16* __restrict__ Clo,
    int K, int ldc, int nx, int mn, int ksplit) {
  // rows padded to 40 bf16 (80 B = 5x16B): 16B-aligned, spread over banks
  __shared__ __align__(16) bf16 As[2][64][40];
  __shared__ __align__(16) bf16 Bs[2][64][40];
  const int t = threadIdx.x;

  const int nwg = gridDim.x;
  const int chunk = nwg >> 3;
  const int virt = (blockIdx.x & 7) * chunk + (blockIdx.x >> 3);
  const int s = virt / mn;
  const int v2 = virt - s * mn;
  const int m0 = (v2 / nx) * 64, n0 = (v2 % nx) * 64;
  const int kb = s * ksplit;

  const int ar = t >> 2, ak = (t & 3) * 8;  // staging: row 0..63, 16B chunk
  const int lane = t & 63, wv = t >> 6;
  const int wm = (wv >> 1) * 32, wn = (wv & 1) * 32;
  const int fr = lane & 15, fg = lane >> 4;

  f32x4 acc[2][2] = {};

  const bf16* pAhi = Ahi + (size_t)(m0 + ar) * K + kb + ak;
  const bf16* pAlo = Alo + (size_t)(m0 + ar) * K + kb + ak;
  const bf16* pBhi = Bhi + (size_t)(n0 + ar) * K + kb + ak;
  const bf16* pBlo = Blo + (size_t)(n0 + ar) * K + kb + ak;

  for (int k0 = 0; k0 < ksplit; k0 += 32) {
    *reinterpret_cast<int4*>(&As[0][ar][ak]) = *reinterpret_cast<const int4*>(pAhi + k0);
    *reinterpret_cast<int4*>(&As[1][ar][ak]) = *reinterpret_cast<const int4*>(pAlo + k0);
    *reinterpret_cast<int4*>(&Bs[0][ar][ak]) = *reinterpret_cast<const int4*>(pBhi + k0);
    *reinterpret_cast<int4*>(&Bs[1][ar][ak]) = *reinterpret_cast<const int4*>(pBlo + k0);
    __syncthreads();

    bf16x8 ah[2], al[2], bh[2], bl[2];
#pragma unroll
    for (int m = 0; m < 2; ++m) {
      ah[m] = *reinterpret_cast<const bf16x8*>(&As[0][wm + m * 16 + fr][fg * 8]);
      al[m] = *reinterpret_cast<const bf16x8*>(&As[1][wm + m * 16 + fr][fg * 8]);
      bh[m] = *reinterpret_cast<const bf16x8*>(&Bs[0][wn + m * 16 + fr][fg * 8]);
      bl[m] = *reinterpret_cast<const bf16x8*>(&Bs[1][wn + m * 16 + fr][fg * 8]);
    }
    // C^T = Bhi*Ahi^T + Blo*Ahi^T + Bhi*Alo^T  (operand-swapped)
#pragma unroll
    for (int m = 0; m < 2; ++m)
#pragma unroll
      for (int n = 0; n < 2; ++n) {
        acc[m][n] = __builtin_amdgcn_mfma_f32_16x16x32_bf16(bh[n], ah[m], acc[m][n], 0, 0, 0);
        acc[m][n] = __builtin_amdgcn_mfma_f32_16x16x32_bf16(bl[n], ah[m], acc[m][n], 0, 0, 0);
        acc[m][n] = __builtin_amdgcn_mfma_f32_16x16x32_bf16(bh[n], al[m], acc[m][n], 0, 0, 0);
      }
    __syncthreads();
  }

  float* __restrict__ Cw = (s == 0) ? C : C2;
#pragma unroll
  for (int m = 0; m < 2; ++m) {
    const int row = m0 + wm + m * 16 + fr;
#pragma unroll
    for (int n = 0; n < 2; ++n) {
      const int col = n0 + wn + n * 16 + fg * 4;  // 4 consecutive cols
      f32x4 v = acc[m][n];
      if constexpr (EPI != EPI_PART) {
        const f32x4 b4 = *reinterpret_cast<const f32x4*>(bias + col);
#pragma unroll
        for (int c = 0; c < 4; ++c) v[c] += b4[c];
      }
      if constexpr (EPI == EPI_BIAS_RELU) {
#pragma unroll
        for (int c = 0; c < 4; ++c) v[c] = fmaxf(v[c], 0.f);
      }
      if constexpr (EPI == EPI_QKV) {
        if (col < 1024) {  // q|k -> bf16 hi/lo, stride 1024 (uniform per block)
          bf16x4 h, l;
#pragma unroll
          for (int c = 0; c < 4; ++c) {
            const bf16 hh = (bf16)v[c];
            h[c] = hh;
            l[c] = (bf16)(v[c] - (float)hh);
          }
          *reinterpret_cast<bf16x4*>(&Chi[(size_t)row * 1024 + col]) = h;
          *reinterpret_cast<bf16x4*>(&Clo[(size_t)row * 1024 + col]) = l;
        } else {  // v -> f32, stride 512
          *reinterpret_cast<f32x4*>(&C[(size_t)row * D_ + col - 1024]) = v;
        }
      } else if constexpr (SPLIT) {
        bf16x4 h, l;
#pragma unroll
        for (int c = 0; c < 4; ++c) {
          const bf16 hh = (bf16)v[c];
          h[c] = hh;
          l[c] = (bf16)(v[c] - (float)hh);
        }
        *reinterpret_cast<bf16x4*>(&Chi[(size_t)row * ldc + col]) = h;
        *reinterpret_cast<bf16x4*>(&Clo[(size_t)row * ldc + col]) = l;
      } else {
        *reinterpret_cast<f32x4*>(&Cw[(size_t)row * ldc + col]) = v;
      }
    }
  }
}

// ---------------------------------------------------------------------------
// Attention phase 1 (MFMA): one block per causal (i-tile64, j-chunk128) pair
// x (b,h). S = Qhi*Khi^T + Qhi*Klo^T + Qlo*Khi^T via mfma_16x16x32_bf16.
// D-frag mapping: query = wv*16 + fg*4 + r, key = jf*16 + fr -> softmax
// reduction = shfl_xor over the 16 fr lanes + 4 jf frags (as before).
// Per-row partial (m, l, d) stats written for the merge kernel.
// ---------------------------------------------------------------------------
__global__ __launch_bounds__(256) void attn_part_kernel(
    const bf16* __restrict__ qk_hi, const bf16* __restrict__ qk_lo,
    const int* __restrict__ lengths,
    float* __restrict__ pm, float* __restrict__ pl, float* __restrict__ pd) {
  __shared__ __align__(16) bf16 Qh[64][72], Ql[64][72];
  __shared__ __align__(16) bf16 Kh[64][72], Kl[64][72];
  const int t = threadIdx.x;
  const int lane = t & 63, wv = t >> 6;
  const int fr = lane & 15, fg = lane >> 4;
  const int bh = blockIdx.y;
  const int bb = bh >> 3, h = bh & 7;

  // unflatten p -> (ib, jc): ib=2a starts at a^2+a, ib=2a+1 starts at (a+1)^2
  const int p = blockIdx.x;
  int a = (int)sqrtf((float)p);
  while ((a + 1) * (a + 1) <= p) ++a;
  while (a * a > p) --a;
  int ib, jc;
  if (p >= a * a + a) { ib = 2 * a;     jc = p - (a * a + a); }
  else                { ib = 2 * a - 1; jc = p - a * a; }

  const int i0 = ib * 64;
  const int len = lengths[bb];
  if (i0 >= len || jc * 128 >= len) return;  // block-uniform: partials unread

  const int sr = t >> 2, sc0 = (t & 3) * 16;  // staging: row, 16-elem segment
  {  // stage Q hi/lo tile
    const size_t gb = (size_t)(bb * S_ + i0 + sr) * 1024 + h * DK_ + sc0;
    *reinterpret_cast<int4*>(&Qh[sr][sc0])     = *reinterpret_cast<const int4*>(qk_hi + gb);
    *reinterpret_cast<int4*>(&Qh[sr][sc0 + 8]) = *reinterpret_cast<const int4*>(qk_hi + gb + 8);
    *reinterpret_cast<int4*>(&Ql[sr][sc0])     = *reinterpret_cast<const int4*>(qk_lo + gb);
    *reinterpret_cast<int4*>(&Ql[sr][sc0 + 8]) = *reinterpret_cast<const int4*>(qk_lo + gb + 8);
  }

  float m_r[4], l_r[4], d_r[4];
#pragma unroll
  for (int r = 0; r < 4; ++r) { m_r[r] = -1e30f; l_r[r] = 0.f; d_r[r] = 0.f; }

  const int jlim = min(i0 + 63, len - 1);
  for (int jt = 0; jt < 2; ++jt) {
    const int j0 = jc * 128 + jt * 64;
    if (j0 > jlim) break;  // uniform
    {  // stage K hi/lo tile
      const size_t gb = (size_t)(bb * S_ + j0 + sr) * 1024 + 512 + h * DK_ + sc0;
      *reinterpret_cast<int4*>(&Kh[sr][sc0])     = *reinterpret_cast<const int4*>(qk_hi + gb);
      *reinterpret_cast<int4*>(&Kh[sr][sc0 + 8]) = *reinterpret_cast<const int4*>(qk_hi + gb + 8);
      *reinterpret_cast<int4*>(&Kl[sr][sc0])     = *reinterpret_cast<const int4*>(qk_lo + gb);
      *reinterpret_cast<int4*>(&Kl[sr][sc0 + 8]) = *reinterpret_cast<const int4*>(qk_lo + gb + 8);
    }
    __syncthreads();

    f32x4 sc[4] = {};
#pragma unroll
    for (int kk = 0; kk < 2; ++kk) {
      const bf16x8 qh = *reinterpret_cast<const bf16x8*>(&Qh[wv * 16 + fr][kk * 32 + fg * 8]);
      const bf16x8 ql = *reinterpret_cast<const bf16x8*>(&Ql[wv * 16 + fr][kk * 32 + fg * 8]);
#pragma unroll
      for (int jf = 0; jf < 4; ++jf) {
        const bf16x8 kh = *reinterpret_cast<const bf16x8*>(&Kh[jf * 16 + fr][kk * 32 + fg * 8]);
        const bf16x8 kl = *reinterpret_cast<const bf16x8*>(&Kl[jf * 16 + fr][kk * 32 + fg * 8]);
        sc[jf] = __builtin_amdgcn_mfma_f32_16x16x32_bf16(qh, kh, sc[jf], 0, 0, 0);
        sc[jf] = __builtin_amdgcn_mfma_f32_16x16x32_bf16(qh, kl, sc[jf], 0, 0, 0);
        sc[jf] = __builtin_amdgcn_mfma_f32_16x16x32_bf16(ql, kh, sc[jf], 0, 0, 0);
      }
    }

    // online softmax row-stats update (state redundant across the 16 fr lanes)
#pragma unroll
    for (int r = 0; r < 4; ++r) {
      const int ig = i0 + wv * 16 + fg * 4 + r;
      float s4[4];
      float mx = -1e30f;
#pragma unroll
      for (int jf = 0; jf < 4; ++jf) {
        const int j = j0 + jf * 16 + fr;
        float v = sc[jf][r];
        if (j > ig || j >= len) v = -1e30f;  // causal + padding mask
        s4[jf] = v;
        mx = fmaxf(mx, v);
      }
#pragma unroll
      for (int off = 1; off < 16; off <<= 1) mx = fmaxf(mx, __shfl_xor(mx, off));
      const float mnew = fmaxf(m_r[r], mx);
      float ps = 0.f, pdg = 0.f;
#pragma unroll
      for (int jf = 0; jf < 4; ++jf) {
        const float e = __expf(s4[jf] - mnew);
        ps += e;
        if (j0 + jf * 16 + fr == ig) pdg = e;  // diagonal numerator
      }
#pragma unroll
      for (int off = 1; off < 16; off <<= 1) {
        ps += __shfl_xor(ps, off);
        pdg += __shfl_xor(pdg, off);
      }
      const float scale = __expf(m_r[r] - mnew);
      l_r[r] = l_r[r] * scale + ps;
      d_r[r] = d_r[r] * scale + pdg;
      m_r[r] = mnew;
    }
    __syncthreads();
  }

  if (fr == 0) {  // one lane per row writes partials
    const size_t base = ((size_t)(bh * 32 + ib) * 16 + jc) * 64;
#pragma unroll
    for (int r = 0; r < 4; ++r) {
      const int row = wv * 16 + fg * 4 + r;
      const float mm = m_r[r];
      const bool ok = mm > -1e29f;  // row saw >=1 valid key in this chunk
      pm[base + row] = mm;
      pl[base + row] = ok ? l_r[r] : 0.f;
      pd[base + row] = ok ? d_r[r] : 0.f;
    }
  }
}

// ---------------------------------------------------------------------------
// Attention phase 2: merge partials per (b,h,i-tile), write wgt=(d/l)*v bf16
// ---------------------------------------------------------------------------
__global__ __launch_bounds__(256) void attn_merge_kernel(
    const float* __restrict__ vsrc, const int* __restrict__ lengths,
    const float* __restrict__ pm, const float* __restrict__ pl,
    const float* __restrict__ pd, bf16* __restrict__ whi, bf16* __restrict__ wlo) {
  __shared__ float msh[4][64], lsh[4][64], dsh[4][64];
  __shared__ float dgs[64];
  const int t = threadIdx.x;
  const int ib = blockIdx.x, bh = blockIdx.y;
  const int bb = bh >> 3, h = bh & 7;
  const int i0 = ib * 64;
  const int len = lengths[bb];

  const int r = t & 63, g = t >> 6;
  float m = -1e30f, l = 0.f, d = 0.f;
  if (i0 < len) {  // else partials unread (poison-safe: dg forced 0 below)
    const int jcmax = min((i0 + 63) >> 7, (len - 1) >> 7);
    const size_t base = ((size_t)(bh * 32 + ib) * 16) * 64 + r;
    for (int jc = g; jc <= jcmax; jc += 4) {
      const size_t idx = base + (size_t)jc * 64;
      const float m2 = pm[idx], l2 = pl[idx], d2 = pd[idx];
      const float mn = fmaxf(m, m2);
      const float e1 = __expf(m - mn), e2 = __expf(m2 - mn);
      l = l * e1 + l2 * e2;
      d = d * e1 + d2 * e2;
      m = mn;
    }
  }
  msh[g][r] = m; lsh[g][r] = l; dsh[g][r] = d;
  __syncthreads();
  if (t < 64) {
    float M = msh[0][t], L = lsh[0][t], Dv = dsh[0][t];
#pragma unroll
    for (int gg = 1; gg < 4; ++gg) {
      const float m2 = msh[gg][t], l2 = lsh[gg][t], d2 = dsh[gg][t];
      const float mn = fmaxf(M, m2);
      const float e1 = __expf(M - mn), e2 = __expf(m2 - mn);
      L = L * e1 + l2 * e2;
      Dv = Dv * e1 + d2 * e2;
      M = mn;
    }
    // valid rows always have the jc=0 partial with l >= 1 -> L >= 1
    dgs[t] = (i0 + t < len) ? Dv / L : 0.f;
  }
  __syncthreads();

  const int rr = t >> 2, q = t & 3;
  const float dg = dgs[rr];
  const size_t obase = (size_t)(bb * S_ + i0 + rr) * D_ + h * DK_;
#pragma unroll
  for (int kk = 0; kk < 4; ++kk) {
    const int col = q * 4 + kk * 16;
    const float4 v4 = *reinterpret_cast<const float4*>(vsrc + obase + col);
    const float vv[4] = {dg * v4.x, dg * v4.y, dg * v4.z, dg * v4.w};
    bf16x4 hh, ll;
#pragma unroll
    for (int c = 0; c < 4; ++c) {
      const bf16 x = (bf16)vv[c];
      hh[c] = x;
      ll[c] = (bf16)(vv[c] - (float)x);
    }
    *reinterpret_cast<bf16x4*>(&whi[obase + col]) = hh;
    *reinterpret_cast<bf16x4*>(&wlo[obase + col]) = ll;
  }
}

// ---------------------------------------------------------------------------
// LN1 fused: h1 = P0 + P1 + bo + mask(x); y1 = LN(h1) written as bf16 hi/lo.
// ---------------------------------------------------------------------------
__global__ __launch_bounds__(256) void ln1_fused_kernel(
    const float* __restrict__ P0, const float* __restrict__ P1,
    const float* __restrict__ x, const int* __restrict__ lengths,
    const float* __restrict__ bo,
    const float* __restrict__ gamma, const float* __restrict__ beta,
    bf16* __restrict__ Yhi, bf16* __restrict__ Ylo) {
  const int row = blockIdx.x;
  const int t = threadIdx.x;
  const int lenb = lengths[row >> 11];
  const bool valid = (row & (S_ - 1)) < lenb;
  const size_t ro = (size_t)row * D_ + t * 2;
  const float2 p0 = *reinterpret_cast<const float2*>(P0 + ro);
  const float2 p1 = *reinterpret_cast<const float2*>(P1 + ro);
  const float2 xv = *reinterpret_cast<const float2*>(x + ro);
  const float2 bv = *reinterpret_cast<const float2*>(bo + t * 2);
  float hx = p0.x + p1.x + bv.x + (valid ? xv.x : 0.f);
  float hy = p0.y + p1.y + bv.y + (valid ? xv.y : 0.f);

  float s = hx + hy, s2 = hx * hx + hy * hy;
#pragma unroll
  for (int off = 1; off < 64; off <<= 1) {
    s += __shfl_xor(s, off);
    s2 += __shfl_xor(s2, off);
  }
  __shared__ float red[8];
  const int w = t >> 6;
  if ((t & 63) == 0) { red[w] = s; red[4 + w] = s2; }
  __syncthreads();
  const float ts  = red[0] + red[1] + red[2] + red[3];
  const float ts2 = red[4] + red[5] + red[6] + red[7];
  const float mean = ts * (1.f / D_);
  const float var  = ts2 * (1.f / D_) - mean * mean;
  const float inv  = 1.f / sqrtf(var + EPS_);
  const float2 g  = *reinterpret_cast<const float2*>(gamma + t * 2);
  const float2 bt = *reinterpret_cast<const float2*>(beta + t * 2);
  const float ox = g.x * ((hx - mean) * inv) + bt.x;
  const float oy = g.y * ((hy - mean) * inv) + bt.y;
  const bf16 ohx = (bf16)ox, ohy = (bf16)oy;
  Yhi[ro] = ohx;  Yhi[ro + 1] = ohy;
  Ylo[ro] = (bf16)(ox - (float)ohx);
  Ylo[ro + 1] = (bf16)(oy - (float)ohy);
}

// ---------------------------------------------------------------------------
// LN2 fused: h2 = Q0 + Q1 + b2 + (y1hi+y1lo); out = LN(h2) f32.
// ---------------------------------------------------------------------------
__global__ __launch_bounds__(256) void ln2_fused_kernel(
    const float* __restrict__ Q0, const float* __restrict__ Q1,
    const bf16* __restrict__ Yhi, const bf16* __restrict__ Ylo,
    const float* __restrict__ b2,
    const float* __restrict__ gamma, const float* __restrict__ beta,
    float* __restrict__ out) {
  const int row = blockIdx.x;
  const int t = threadIdx.x;
  const size_t ro = (size_t)row * D_ + t * 2;
  const float2 q0 = *reinterpret_cast<const float2*>(Q0 + ro);
  const float2 q1 = *reinterpret_cast<const float2*>(Q1 + ro);
  const float2 bv = *reinterpret_cast<const float2*>(b2 + t * 2);
  const float y1x = (float)Yhi[ro] + (float)Ylo[ro];
  const float y1y = (float)Yhi[ro + 1] + (float)Ylo[ro + 1];
  float hx = q0.x + q1.x + bv.x + y1x;
  float hy = q0.y + q1.y + bv.y + y1y;

  float s = hx + hy, s2 = hx * hx + hy * hy;
#pragma unroll
  for (int off = 1; off < 64; off <<= 1) {
    s += __shfl_xor(s, off);
    s2 += __shfl_xor(s2, off);
  }
  __shared__ float red[8];
  const int w = t >> 6;
  if ((t & 63) == 0) { red[w] = s; red[4 + w] = s2; }
  __syncthreads();
  const float ts  = red[0] + red[1] + red[2] + red[3];
  const float ts2 = red[4] + red[5] + red[6] + red[7];
  const float mean = ts * (1.f / D_);
  const float var  = ts2 * (1.f / D_) - mean * mean;
  const float inv  = 1.f / sqrtf(var + EPS_);
  const float2 g  = *reinterpret_cast<const float2*>(gamma + t * 2);
  const float2 bt = *reinterpret_cast<const float2*>(beta + t * 2);
  float2 o;
  o.x = g.x * ((hx - mean) * inv) + bt.x;
  o.y = g.y * ((hy - mean) * inv) + bt.y;
  *reinterpret_cast<float2*>(out + ro) = o;
}

// ---------------------------------------------------------------------------
extern "C" void kernel_launch(void* const* d_in, const int* in_sizes, int n_in,
                              void* d_out, int out_size, void* d_ws, size_t ws_size,
                              hipStream_t stream) {
  const float* x       = (const float*)d_in[0];
  const int*   lengths = (const int*)d_in[1];
  const float* Wq = (const float*)d_in[2];
  const float* bq = (const float*)d_in[3];
  const float* Wk = (const float*)d_in[4];
  const float* bk = (const float*)d_in[5];
  const float* Wv = (const float*)d_in[6];
  const float* bv = (const float*)d_in[7];
  const float* Wo = (const float*)d_in[8];
  const float* bo = (const float*)d_in[9];
  const float* W1 = (const float*)d_in[10];
  const float* b1 = (const float*)d_in[11];
  const float* W2 = (const float*)d_in[12];
  const float* b2 = (const float*)d_in[13];
  const float* gamma1 = (const float*)d_in[14];
  const float* beta1  = (const float*)d_in[15];
  const float* gamma2 = (const float*)d_in[16];
  const float* beta2  = (const float*)d_in[17];
  float* out = (float*)d_out;

  char* ws = (char*)d_ws;
  // ---- workspace layout (lifetime-overlapped, < 64 MB) ----
  // weights (live until their GEMM completes):
  bf16*  qkvT_hi = (bf16*)(ws + 0);          // [1536][512]
  bf16*  qkvT_lo = (bf16*)(ws + 1572864);
  bf16*  WoT_hi  = (bf16*)(ws + 3145728);    // [512][512]
  bf16*  WoT_lo  = (bf16*)(ws + 3670016);
  bf16*  W1T_hi  = (bf16*)(ws + 4194304);    // [2048][512]
  bf16*  W1T_lo  = (bf16*)(ws + 6291456);
  bf16*  W2T_hi  = (bf16*)(ws + 8388608);    // [512][2048]
  bf16*  W2T_lo  = (bf16*)(ws + 10485760);
  float* bqkv    = (float*)(ws + 12582912);  // [1536]
  // region A: qk hi/lo + v f32 (24MB) -> Wo partials P0/P1 -> ff1 hi/lo
  bf16*  qk_hi   = (bf16*)(ws + 12589056);   // [4096][1024]
  bf16*  qk_lo   = (bf16*)(ws + 20977664);
  float* v_f32   = (float*)(ws + 29366272);  // [4096][512], ends 37754880
  float* P0      = (float*)(ws + 12589056);  // [4096][512] (qk dead after attn_part)
  float* P1      = (float*)(ws + 20977664);
  float* part_m  = (float*)(ws + 37754880);  // attn partials, 6MB window
  float* part_l  = (float*)(ws + 39852032);
  float* part_d  = (float*)(ws + 41949184);  // ends 44046336
  bf16*  ff1_hi  = (bf16*)(ws + 12589056);   // [4096][2048] (after LN1)
  bf16*  ff1_lo  = (bf16*)(ws + 29366272);   // ends 46143488
  // region B: xm hi/lo -> y1 hi/lo (live through LN2)
  bf16*  xm_hi   = (bf16*)(ws + 46143488);   // [4096][512]
  bf16*  xm_lo   = (bf16*)(ws + 50337792);
  bf16*  y1_hi   = (bf16*)(ws + 46143488);
  bf16*  y1_lo   = (bf16*)(ws + 50337792);
  // region C: wgt hi/lo -> FF2 partial Q0
  bf16*  wgt_hi  = (bf16*)(ws + 54532096);   // [4096][512]
  bf16*  wgt_lo  = (bf16*)(ws + 58726400);   // ends 62920704
  float* Q0      = (float*)(ws + 54532096);  // (after Wo)
  // FF2 partial Q1 over dead qkvT/WoT/W1T weights (after FF1):
  float* Q1      = (float*)(ws + 0);         // [4096][512] = 8.4MB, ends 8388608

  const dim3 blk(256);
  const int M = B_ * S_;  // 4096

  // 1) weight transposes + hi/lo splits
  Trans4Args ta;
  ta.w[0] = Wq; ta.w[1] = Wk; ta.w[2] = Wv; ta.w[3] = Wo;
  ta.thi[0] = qkvT_hi; ta.thi[1] = qkvT_hi; ta.thi[2] = qkvT_hi; ta.thi[3] = WoT_hi;
  ta.tlo[0] = qkvT_lo; ta.tlo[1] = qkvT_lo; ta.tlo[2] = qkvT_lo; ta.tlo[3] = WoT_lo;
  ta.rowOff[0] = 0; ta.rowOff[1] = 512; ta.rowOff[2] = 1024; ta.rowOff[3] = 0;
  transpose4_kernel<<<dim3(16, 16, 4), blk, 0, stream>>>(ta);
  transpose_split_kernel<<<dim3(64, 16), blk, 0, stream>>>(W1, 512, 2048, W1T_hi, W1T_lo);
  transpose_split_kernel<<<dim3(16, 64), blk, 0, stream>>>(W2, 2048, 512, W2T_hi, W2T_lo);
  pack_bias_kernel<<<dim3(6), blk, 0, stream>>>(bq, bk, bv, bqkv);

  // 2) mask + split
  mask_split_kernel<<<dim3((M * D_ / 4) / 256), blk, 0, stream>>>(x, lengths, xm_hi, xm_lo);

  // 3) fused QKV GEMM -> qk hi/lo (bf16) + v (f32).  grid 64x24 = 1536
  gemm_kernel<EPI_QKV, false><<<dim3(1536), blk, 0, stream>>>(
      xm_hi, xm_lo, qkvT_hi, qkvT_lo, bqkv,
      v_f32, nullptr, qk_hi, qk_lo, 512, QS_, 24, 1536, 512);

  // 4) attention: MFMA partials (272 causal pairs x 16 bh) + merge
  attn_part_kernel<<<dim3(272, 16), blk, 0, stream>>>(qk_hi, qk_lo, lengths,
                                                      part_m, part_l, part_d);
  attn_merge_kernel<<<dim3(32, 16), blk, 0, stream>>>(v_f32, lengths, part_m, part_l, part_d,
                                                      wgt_hi, wgt_lo);

  // 5) O-proj split-K=2 partials.  grid 2x64x8 = 1024
  gemm_kernel<EPI_PART, false><<<dim3(1024), blk, 0, stream>>>(
      wgt_hi, wgt_lo, WoT_hi, WoT_lo, nullptr,
      P0, P1, nullptr, nullptr, 512, D_, 8, 512, 256);

  // 6) LN1 fused (P0+P1+bo+mask(x)) -> y1 hi/lo
  ln1_fused_kernel<<<dim3(M), blk, 0, stream>>>(P0, P1, x, lengths, bo,
                                                gamma1, beta1, y1_hi, y1_lo);

  // 7) FF1 (+bias+relu) -> ff1 hi/lo.  grid 64x32 = 2048
  gemm_kernel<EPI_BIAS_RELU, true><<<dim3(2048), blk, 0, stream>>>(
      y1_hi, y1_lo, W1T_hi, W1T_lo, b1,
      nullptr, nullptr, ff1_hi, ff1_lo, 512, FF_, 32, 2048, 512);

  // 8) FF2 split-K=2 partials.  grid 2x64x8 = 1024
  gemm_kernel<EPI_PART, false><<<dim3(1024), blk, 0, stream>>>(
      ff1_hi, ff1_lo, W2T_hi, W2T_lo, nullptr,
      Q0, Q1, nullptr, nullptr, FF_, D_, 8, 512, 1024);

  // 9) LN2 fused (Q0+Q1+b2+y1) -> out
  ln2_fused_kernel<<<dim3(M), blk, 0, stream>>>(Q0, Q1, y1_hi, y1_lo, b2,
                                                gamma2, beta2, out);
}

// Round 9
// 266.196 us; speedup vs baseline: 1.1555x; 1.0751x over previous
//
#include <hip/hip_runtime.h>

// Problem constants (match reference file)
#define B_   2
#define S_   2048
#define D_   512
#define H_   8
#define DK_  64
#define FF_  2048
#define EPS_ 1e-3f
#define QS_  1536   // fused QKV output width (q|k|v)

typedef __bf16 bf16;
typedef __bf16 bf16x4 __attribute__((ext_vector_type(4)));
typedef __bf16 bf16x8 __attribute__((ext_vector_type(8)));
typedef float  f32x4  __attribute__((ext_vector_type(4)));

// async global->LDS, 16B per lane, LDS dest = wave-uniform base + lane*16
__device__ __forceinline__ void gload16(const bf16* g, bf16* l) {
  __builtin_amdgcn_global_load_lds(
      (__attribute__((address_space(1))) void*)g,
      (__attribute__((address_space(3))) void*)l, 16, 0, 0);
}

// ---------------------------------------------------------------------------
// Weight transpose + hi/lo bf16 split:  W[K][N] -> T{hi,lo}[rowOff+n][k]
// ---------------------------------------------------------------------------
struct Trans4Args {
  const float* w[4];
  bf16* thi[4];
  bf16* tlo[4];
  int rowOff[4];
};

__global__ __launch_bounds__(256) void transpose4_kernel(Trans4Args a) {
  __shared__ float tl[32][33];
  const int t = threadIdx.x;
  const int tx = t & 31, ty = t >> 5;  // 32 x 8
  const int n0 = blockIdx.x * 32, k0 = blockIdx.y * 32;
  const int wsel = blockIdx.z;
  const float* __restrict__ W = a.w[wsel];
#pragma unroll
  for (int r = 0; r < 32; r += 8)
    tl[r + ty][tx] = W[(size_t)(k0 + r + ty) * 512 + n0 + tx];
  __syncthreads();
  bf16* __restrict__ Thi = a.thi[wsel];
  bf16* __restrict__ Tlo = a.tlo[wsel];
  const int ro = a.rowOff[wsel];
#pragma unroll
  for (int r = 0; r < 32; r += 8) {
    const int n = r + ty;
    const float v = tl[tx][n];  // stride-33 -> conflict-free
    const bf16 h = (bf16)v;
    const size_t o = (size_t)(ro + n0 + n) * 512 + k0 + tx;
    Thi[o] = h;
    Tlo[o] = (bf16)(v - (float)h);
  }
}

__global__ __launch_bounds__(256) void transpose_split_kernel(
    const float* __restrict__ W, int K, int N,
    bf16* __restrict__ Thi, bf16* __restrict__ Tlo) {
  __shared__ float tl[32][33];
  const int t = threadIdx.x;
  const int tx = t & 31, ty = t >> 5;
  const int n0 = blockIdx.x * 32, k0 = blockIdx.y * 32;
#pragma unroll
  for (int r = 0; r < 32; r += 8)
    tl[r + ty][tx] = W[(size_t)(k0 + r + ty) * N + n0 + tx];
  __syncthreads();
#pragma unroll
  for (int r = 0; r < 32; r += 8) {
    const int n = r + ty;
    const float v = tl[tx][n];
    const bf16 h = (bf16)v;
    const size_t o = (size_t)(n0 + n) * K + k0 + tx;
    Thi[o] = h;
    Tlo[o] = (bf16)(v - (float)h);
  }
}

__global__ __launch_bounds__(256) void pack_bias_kernel(const float* __restrict__ bq,
                                                        const float* __restrict__ bk,
                                                        const float* __restrict__ bv,
                                                        float* __restrict__ out) {
  const int i = blockIdx.x * 256 + threadIdx.x;  // 0..1535
  out[i] = (i < 512) ? bq[i] : (i < 1024) ? bk[i - 512] : bv[i - 1024];
}

// ---------------------------------------------------------------------------
// Pad-mask + hi/lo split
// ---------------------------------------------------------------------------
__global__ __launch_bounds__(256) void mask_split_kernel(const float* __restrict__ x,
                                                         const int* __restrict__ lengths,
                                                         bf16* __restrict__ xhi,
                                                         bf16* __restrict__ xlo) {
  const int idx = blockIdx.x * 256 + threadIdx.x;
  const int d4 = D_ / 4;
  const int s = (idx / d4) & (S_ - 1);
  const int b = idx / (d4 * S_);
  float4 v = reinterpret_cast<const float4*>(x)[idx];
  if (s >= lengths[b]) { v.x = 0.f; v.y = 0.f; v.z = 0.f; v.w = 0.f; }
  const float vv[4] = {v.x, v.y, v.z, v.w};
  bf16x4 h, l;
#pragma unroll
  for (int c = 0; c < 4; ++c) {
    const bf16 hh = (bf16)vv[c];
    h[c] = hh;
    l[c] = (bf16)(vv[c] - (float)hh);
  }
  reinterpret_cast<bf16x4*>(xhi)[idx] = h;
  reinterpret_cast<bf16x4*>(xlo)[idx] = l;
}

// ---------------------------------------------------------------------------
// Split-bf16 MFMA GEMM, m97 structure: 128 x BN tile (BN in {128,64}), BK=32,
// 256 thr = 4 waves (2x2 -> per-wave 64 x BN/2). global_load_lds width-16
// staging into LINEAR LDS [row][32]; bank conflicts on fragment reads fixed
// by SOURCE-side chunk swizzle (chunk ^= (row>>1)&3) applied identically on
// the staging source address and the ds_read address (rule: both sides).
// 3 MFMA products per acc (hi*hi + hi*lo + lo*hi) ~ fp32 accuracy.
// OPERAND-SWAPPED epilogue (R8-verified): lane holds C[row=mtile+fr]
// [cols ntile + fg*4 .. +3] -> f32x4/bf16x4 vector stores.
// Split-K: partial s=1 writes to C2 (no bias); downstream LN sums partials.
// ---------------------------------------------------------------------------
enum { EPI_BIAS_RELU = 2, EPI_PART = 4, EPI_QKV = 5 };

template <int EPI, bool SPLIT, int BN>
__global__ __launch_bounds__(256) void gemm_kernel(
    const bf16* __restrict__ Ahi, const bf16* __restrict__ Alo,
    const bf16* __restrict__ Bhi, const bf16* __restrict__ Blo,
    const float* __restrict__ bias,
    float* __restrict__ C, float* __restrict__ C2,
    bf16* __restrict__ Chi, bf16* __restrict__ Clo,
    int K, int ldc, int nx, int mn, int ksplit) {
  constexpr int NR = BN / 32;  // n-frags per wave
  __shared__ __align__(16) bf16 As[2][128][32];  // [hi/lo][row][k], linear
  __shared__ __align__(16) bf16 Bs[2][BN][32];
  const int t = threadIdx.x;

  const int nwg = gridDim.x;
  const int chunk = nwg >> 3;
  const int virt = (blockIdx.x & 7) * chunk + (blockIdx.x >> 3);
  const int s = virt / mn;
  const int v2 = virt - s * mn;
  const int m0 = (v2 / nx) * 128, n0 = (v2 % nx) * BN;
  const int kb = s * ksplit;

  const int lane = t & 63, wv = t >> 6;
  const int fr = lane & 15, fg = lane >> 4;
  const int wm = (wv >> 1) * 64, wn = (wv & 1) * (BN / 2);
  const int sr = lane >> 2, sslot = lane & 3;  // staging: 16 rows x 4 chunks

  f32x4 acc[4][NR] = {};

  const bf16* gAh = Ahi + (size_t)m0 * K + kb;
  const bf16* gAl = Alo + (size_t)m0 * K + kb;
  const bf16* gBh = Bhi + (size_t)n0 * K + kb;
  const bf16* gBl = Blo + (size_t)n0 * K + kb;

  for (int k0 = 0; k0 < ksplit; k0 += 32) {
    // ---- async staging: per wave-instr 64 lanes x 16B = 16 rows ----
#pragma unroll
    for (int q = 0; q < 2; ++q) {  // A: 32 rows per wave
      const int r = wv * 32 + q * 16 + sr;
      const int ch = sslot ^ ((r >> 1) & 3);  // source swizzle
      const size_t go = (size_t)r * K + k0 + ch * 8;
      gload16(gAh + go, &As[0][wv * 32 + q * 16][0]);
      gload16(gAl + go, &As[1][wv * 32 + q * 16][0]);
    }
    if constexpr (BN == 128) {
#pragma unroll
      for (int q = 0; q < 2; ++q) {
        const int r = wv * 32 + q * 16 + sr;
        const int ch = sslot ^ ((r >> 1) & 3);
        const size_t go = (size_t)r * K + k0 + ch * 8;
        gload16(gBh + go, &Bs[0][wv * 32 + q * 16][0]);
        gload16(gBl + go, &Bs[1][wv * 32 + q * 16][0]);
      }
    } else {  // BN == 64: 16 rows per wave
      const int r = wv * 16 + sr;
      const int ch = sslot ^ ((r >> 1) & 3);
      const size_t go = (size_t)r * K + k0 + ch * 8;
      gload16(gBh + go, &Bs[0][wv * 16][0]);
      gload16(gBl + go, &Bs[1][wv * 16][0]);
    }
    __syncthreads();  // compiler inserts vmcnt(0) drain before barrier

    bf16x8 ah[4], al[4], bh[NR], bl[NR];
#pragma unroll
    for (int m = 0; m < 4; ++m) {
      const int r = wm + m * 16 + fr;
      const int ch = fg ^ ((r >> 1) & 3);  // same swizzle on read
      ah[m] = *reinterpret_cast<const bf16x8*>(&As[0][r][ch * 8]);
      al[m] = *reinterpret_cast<const bf16x8*>(&As[1][r][ch * 8]);
    }
#pragma unroll
    for (int n = 0; n < NR; ++n) {
      const int r = wn + n * 16 + fr;
      const int ch = fg ^ ((r >> 1) & 3);
      bh[n] = *reinterpret_cast<const bf16x8*>(&Bs[0][r][ch * 8]);
      bl[n] = *reinterpret_cast<const bf16x8*>(&Bs[1][r][ch * 8]);
    }
    // C^T fragments: mfma(B, A) (operand-swapped)
#pragma unroll
    for (int m = 0; m < 4; ++m)
#pragma unroll
      for (int n = 0; n < NR; ++n) {
        acc[m][n] = __builtin_amdgcn_mfma_f32_16x16x32_bf16(bh[n], ah[m], acc[m][n], 0, 0, 0);
        acc[m][n] = __builtin_amdgcn_mfma_f32_16x16x32_bf16(bl[n], ah[m], acc[m][n], 0, 0, 0);
        acc[m][n] = __builtin_amdgcn_mfma_f32_16x16x32_bf16(bh[n], al[m], acc[m][n], 0, 0, 0);
      }
    __syncthreads();
  }

  float* __restrict__ Cw = (s == 0) ? C : C2;
#pragma unroll
  for (int m = 0; m < 4; ++m) {
    const int row = m0 + wm + m * 16 + fr;
#pragma unroll
    for (int n = 0; n < NR; ++n) {
      const int col = n0 + wn + n * 16 + fg * 4;  // 4 consecutive cols
      f32x4 v = acc[m][n];
      if constexpr (EPI != EPI_PART) {
        const f32x4 b4 = *reinterpret_cast<const f32x4*>(bias + col);
#pragma unroll
        for (int c = 0; c < 4; ++c) v[c] += b4[c];
      }
      if constexpr (EPI == EPI_BIAS_RELU) {
#pragma unroll
        for (int c = 0; c < 4; ++c) v[c] = fmaxf(v[c], 0.f);
      }
      if constexpr (EPI == EPI_QKV) {
        if (col < 1024) {  // q|k -> bf16 hi/lo, stride 1024 (uniform per block)
          bf16x4 h, l;
#pragma unroll
          for (int c = 0; c < 4; ++c) {
            const bf16 hh = (bf16)v[c];
            h[c] = hh;
            l[c] = (bf16)(v[c] - (float)hh);
          }
          *reinterpret_cast<bf16x4*>(&Chi[(size_t)row * 1024 + col]) = h;
          *reinterpret_cast<bf16x4*>(&Clo[(size_t)row * 1024 + col]) = l;
        } else {  // v -> f32, stride 512
          *reinterpret_cast<f32x4*>(&C[(size_t)row * D_ + col - 1024]) = v;
        }
      } else if constexpr (SPLIT) {
        bf16x4 h, l;
#pragma unroll
        for (int c = 0; c < 4; ++c) {
          const bf16 hh = (bf16)v[c];
          h[c] = hh;
          l[c] = (bf16)(v[c] - (float)hh);
        }
        *reinterpret_cast<bf16x4*>(&Chi[(size_t)row * ldc + col]) = h;
        *reinterpret_cast<bf16x4*>(&Clo[(size_t)row * ldc + col]) = l;
      } else {
        *reinterpret_cast<f32x4*>(&Cw[(size_t)row * ldc + col]) = v;
      }
    }
  }
}

// ---------------------------------------------------------------------------
// Attention phase 1 (MFMA): one block per causal (i-tile64, j-chunk128) pair
// x (b,h). S = Qhi*Khi^T + Qhi*Klo^T + Qlo*Khi^T via mfma_16x16x32_bf16.
// D-frag mapping: query = wv*16 + fg*4 + r, key = jf*16 + fr -> softmax
// reduction = shfl_xor over the 16 fr lanes + 4 jf frags.
// ---------------------------------------------------------------------------
__global__ __launch_bounds__(256) void attn_part_kernel(
    const bf16* __restrict__ qk_hi, const bf16* __restrict__ qk_lo,
    const int* __restrict__ lengths,
    float* __restrict__ pm, float* __restrict__ pl, float* __restrict__ pd) {
  __shared__ __align__(16) bf16 Qh[64][72], Ql[64][72];
  __shared__ __align__(16) bf16 Kh[64][72], Kl[64][72];
  const int t = threadIdx.x;
  const int lane = t & 63, wv = t >> 6;
  const int fr = lane & 15, fg = lane >> 4;
  const int bh = blockIdx.y;
  const int bb = bh >> 3, h = bh & 7;

  // unflatten p -> (ib, jc): ib=2a starts at a^2+a, ib=2a+1 starts at (a+1)^2
  const int p = blockIdx.x;
  int a = (int)sqrtf((float)p);
  while ((a + 1) * (a + 1) <= p) ++a;
  while (a * a > p) --a;
  int ib, jc;
  if (p >= a * a + a) { ib = 2 * a;     jc = p - (a * a + a); }
  else                { ib = 2 * a - 1; jc = p - a * a; }

  const int i0 = ib * 64;
  const int len = lengths[bb];
  if (i0 >= len || jc * 128 >= len) return;  // block-uniform: partials unread

  const int sr = t >> 2, sc0 = (t & 3) * 16;  // staging: row, 16-elem segment
  {  // stage Q hi/lo tile
    const size_t gb = (size_t)(bb * S_ + i0 + sr) * 1024 + h * DK_ + sc0;
    *reinterpret_cast<int4*>(&Qh[sr][sc0])     = *reinterpret_cast<const int4*>(qk_hi + gb);
    *reinterpret_cast<int4*>(&Qh[sr][sc0 + 8]) = *reinterpret_cast<const int4*>(qk_hi + gb + 8);
    *reinterpret_cast<int4*>(&Ql[sr][sc0])     = *reinterpret_cast<const int4*>(qk_lo + gb);
    *reinterpret_cast<int4*>(&Ql[sr][sc0 + 8]) = *reinterpret_cast<const int4*>(qk_lo + gb + 8);
  }

  float m_r[4], l_r[4], d_r[4];
#pragma unroll
  for (int r = 0; r < 4; ++r) { m_r[r] = -1e30f; l_r[r] = 0.f; d_r[r] = 0.f; }

  const int jlim = min(i0 + 63, len - 1);
  for (int jt = 0; jt < 2; ++jt) {
    const int j0 = jc * 128 + jt * 64;
    if (j0 > jlim) break;  // uniform
    {  // stage K hi/lo tile
      const size_t gb = (size_t)(bb * S_ + j0 + sr) * 1024 + 512 + h * DK_ + sc0;
      *reinterpret_cast<int4*>(&Kh[sr][sc0])     = *reinterpret_cast<const int4*>(qk_hi + gb);
      *reinterpret_cast<int4*>(&Kh[sr][sc0 + 8]) = *reinterpret_cast<const int4*>(qk_hi + gb + 8);
      *reinterpret_cast<int4*>(&Kl[sr][sc0])     = *reinterpret_cast<const int4*>(qk_lo + gb);
      *reinterpret_cast<int4*>(&Kl[sr][sc0 + 8]) = *reinterpret_cast<const int4*>(qk_lo + gb + 8);
    }
    __syncthreads();

    f32x4 sc[4] = {};
#pragma unroll
    for (int kk = 0; kk < 2; ++kk) {
      const bf16x8 qh = *reinterpret_cast<const bf16x8*>(&Qh[wv * 16 + fr][kk * 32 + fg * 8]);
      const bf16x8 ql = *reinterpret_cast<const bf16x8*>(&Ql[wv * 16 + fr][kk * 32 + fg * 8]);
#pragma unroll
      for (int jf = 0; jf < 4; ++jf) {
        const bf16x8 kh = *reinterpret_cast<const bf16x8*>(&Kh[jf * 16 + fr][kk * 32 + fg * 8]);
        const bf16x8 kl = *reinterpret_cast<const bf16x8*>(&Kl[jf * 16 + fr][kk * 32 + fg * 8]);
        sc[jf] = __builtin_amdgcn_mfma_f32_16x16x32_bf16(qh, kh, sc[jf], 0, 0, 0);
        sc[jf] = __builtin_amdgcn_mfma_f32_16x16x32_bf16(qh, kl, sc[jf], 0, 0, 0);
        sc[jf] = __builtin_amdgcn_mfma_f32_16x16x32_bf16(ql, kh, sc[jf], 0, 0, 0);
      }
    }

    // online softmax row-stats update (state redundant across the 16 fr lanes)
#pragma unroll
    for (int r = 0; r < 4; ++r) {
      const int ig = i0 + wv * 16 + fg * 4 + r;
      float s4[4];
      float mx = -1e30f;
#pragma unroll
      for (int jf = 0; jf < 4; ++jf) {
        const int j = j0 + jf * 16 + fr;
        float v = sc[jf][r];
        if (j > ig || j >= len) v = -1e30f;  // causal + padding mask
        s4[jf] = v;
        mx = fmaxf(mx, v);
      }
#pragma unroll
      for (int off = 1; off < 16; off <<= 1) mx = fmaxf(mx, __shfl_xor(mx, off));
      const float mnew = fmaxf(m_r[r], mx);
      float ps = 0.f, pdg = 0.f;
#pragma unroll
      for (int jf = 0; jf < 4; ++jf) {
        const float e = __expf(s4[jf] - mnew);
        ps += e;
        if (j0 + jf * 16 + fr == ig) pdg = e;  // diagonal numerator
      }
#pragma unroll
      for (int off = 1; off < 16; off <<= 1) {
        ps += __shfl_xor(ps, off);
        pdg += __shfl_xor(pdg, off);
      }
      const float scale = __expf(m_r[r] - mnew);
      l_r[r] = l_r[r] * scale + ps;
      d_r[r] = d_r[r] * scale + pdg;
      m_r[r] = mnew;
    }
    __syncthreads();
  }

  if (fr == 0) {  // one lane per row writes partials
    const size_t base = ((size_t)(bh * 32 + ib) * 16 + jc) * 64;
#pragma unroll
    for (int r = 0; r < 4; ++r) {
      const int row = wv * 16 + fg * 4 + r;
      const float mm = m_r[r];
      const bool ok = mm > -1e29f;  // row saw >=1 valid key in this chunk
      pm[base + row] = mm;
      pl[base + row] = ok ? l_r[r] : 0.f;
      pd[base + row] = ok ? d_r[r] : 0.f;
    }
  }
}

// ---------------------------------------------------------------------------
// Attention phase 2: merge partials per (b,h,i-tile), write wgt=(d/l)*v bf16
// ---------------------------------------------------------------------------
__global__ __launch_bounds__(256) void attn_merge_kernel(
    const float* __restrict__ vsrc, const int* __restrict__ lengths,
    const float* __restrict__ pm, const float* __restrict__ pl,
    const float* __restrict__ pd, bf16* __restrict__ whi, bf16* __restrict__ wlo) {
  __shared__ float msh[4][64], lsh[4][64], dsh[4][64];
  __shared__ float dgs[64];
  const int t = threadIdx.x;
  const int ib = blockIdx.x, bh = blockIdx.y;
  const int bb = bh >> 3, h = bh & 7;
  const int i0 = ib * 64;
  const int len = lengths[bb];

  const int r = t & 63, g = t >> 6;
  float m = -1e30f, l = 0.f, d = 0.f;
  if (i0 < len) {  // else partials unread (poison-safe: dg forced 0 below)
    const int jcmax = min((i0 + 63) >> 7, (len - 1) >> 7);
    const size_t base = ((size_t)(bh * 32 + ib) * 16) * 64 + r;
    for (int jc = g; jc <= jcmax; jc += 4) {
      const size_t idx = base + (size_t)jc * 64;
      const float m2 = pm[idx], l2 = pl[idx], d2 = pd[idx];
      const float mn = fmaxf(m, m2);
      const float e1 = __expf(m - mn), e2 = __expf(m2 - mn);
      l = l * e1 + l2 * e2;
      d = d * e1 + d2 * e2;
      m = mn;
    }
  }
  msh[g][r] = m; lsh[g][r] = l; dsh[g][r] = d;
  __syncthreads();
  if (t < 64) {
    float M = msh[0][t], L = lsh[0][t], Dv = dsh[0][t];
#pragma unroll
    for (int gg = 1; gg < 4; ++gg) {
      const float m2 = msh[gg][t], l2 = lsh[gg][t], d2 = dsh[gg][t];
      const float mn = fmaxf(M, m2);
      const float e1 = __expf(M - mn), e2 = __expf(m2 - mn);
      L = L * e1 + l2 * e2;
      Dv = Dv * e1 + d2 * e2;
      M = mn;
    }
    // valid rows always have the jc=0 partial with l >= 1 -> L >= 1
    dgs[t] = (i0 + t < len) ? Dv / L : 0.f;
  }
  __syncthreads();

  const int rr = t >> 2, q = t & 3;
  const float dg = dgs[rr];
  const size_t obase = (size_t)(bb * S_ + i0 + rr) * D_ + h * DK_;
#pragma unroll
  for (int kk = 0; kk < 4; ++kk) {
    const int col = q * 4 + kk * 16;
    const float4 v4 = *reinterpret_cast<const float4*>(vsrc + obase + col);
    const float vv[4] = {dg * v4.x, dg * v4.y, dg * v4.z, dg * v4.w};
    bf16x4 hh, ll;
#pragma unroll
    for (int c = 0; c < 4; ++c) {
      const bf16 x = (bf16)vv[c];
      hh[c] = x;
      ll[c] = (bf16)(vv[c] - (float)x);
    }
    *reinterpret_cast<bf16x4*>(&whi[obase + col]) = hh;
    *reinterpret_cast<bf16x4*>(&wlo[obase + col]) = ll;
  }
}

// ---------------------------------------------------------------------------
// LN1 fused: h1 = P0 + P1 + bo + mask(x); y1 = LN(h1) written as bf16 hi/lo.
// ---------------------------------------------------------------------------
__global__ __launch_bounds__(256) void ln1_fused_kernel(
    const float* __restrict__ P0, const float* __restrict__ P1,
    const float* __restrict__ x, const int* __restrict__ lengths,
    const float* __restrict__ bo,
    const float* __restrict__ gamma, const float* __restrict__ beta,
    bf16* __restrict__ Yhi, bf16* __restrict__ Ylo) {
  const int row = blockIdx.x;
  const int t = threadIdx.x;
  const int lenb = lengths[row >> 11];
  const bool valid = (row & (S_ - 1)) < lenb;
  const size_t ro = (size_t)row * D_ + t * 2;
  const float2 p0 = *reinterpret_cast<const float2*>(P0 + ro);
  const float2 p1 = *reinterpret_cast<const float2*>(P1 + ro);
  const float2 xv = *reinterpret_cast<const float2*>(x + ro);
  const float2 bv = *reinterpret_cast<const float2*>(bo + t * 2);
  float hx = p0.x + p1.x + bv.x + (valid ? xv.x : 0.f);
  float hy = p0.y + p1.y + bv.y + (valid ? xv.y : 0.f);

  float s = hx + hy, s2 = hx * hx + hy * hy;
#pragma unroll
  for (int off = 1; off < 64; off <<= 1) {
    s += __shfl_xor(s, off);
    s2 += __shfl_xor(s2, off);
  }
  __shared__ float red[8];
  const int w = t >> 6;
  if ((t & 63) == 0) { red[w] = s; red[4 + w] = s2; }
  __syncthreads();
  const float ts  = red[0] + red[1] + red[2] + red[3];
  const float ts2 = red[4] + red[5] + red[6] + red[7];
  const float mean = ts * (1.f / D_);
  const float var  = ts2 * (1.f / D_) - mean * mean;
  const float inv  = 1.f / sqrtf(var + EPS_);
  const float2 g  = *reinterpret_cast<const float2*>(gamma + t * 2);
  const float2 bt = *reinterpret_cast<const float2*>(beta + t * 2);
  const float ox = g.x * ((hx - mean) * inv) + bt.x;
  const float oy = g.y * ((hy - mean) * inv) + bt.y;
  const bf16 ohx = (bf16)ox, ohy = (bf16)oy;
  Yhi[ro] = ohx;  Yhi[ro + 1] = ohy;
  Ylo[ro] = (bf16)(ox - (float)ohx);
  Ylo[ro + 1] = (bf16)(oy - (float)ohy);
}

// ---------------------------------------------------------------------------
// LN2 fused: h2 = Q0 + Q1 + b2 + (y1hi+y1lo); out = LN(h2) f32.
// ---------------------------------------------------------------------------
__global__ __launch_bounds__(256) void ln2_fused_kernel(
    const float* __restrict__ Q0, const float* __restrict__ Q1,
    const bf16* __restrict__ Yhi, const bf16* __restrict__ Ylo,
    const float* __restrict__ b2,
    const float* __restrict__ gamma, const float* __restrict__ beta,
    float* __restrict__ out) {
  const int row = blockIdx.x;
  const int t = threadIdx.x;
  const size_t ro = (size_t)row * D_ + t * 2;
  const float2 q0 = *reinterpret_cast<const float2*>(Q0 + ro);
  const float2 q1 = *reinterpret_cast<const float2*>(Q1 + ro);
  const float2 bv = *reinterpret_cast<const float2*>(b2 + t * 2);
  const float y1x = (float)Yhi[ro] + (float)Ylo[ro];
  const float y1y = (float)Yhi[ro + 1] + (float)Ylo[ro + 1];
  float hx = q0.x + q1.x + bv.x + y1x;
  float hy = q0.y + q1.y + bv.y + y1y;

  float s = hx + hy, s2 = hx * hx + hy * hy;
#pragma unroll
  for (int off = 1; off < 64; off <<= 1) {
    s += __shfl_xor(s, off);
    s2 += __shfl_xor(s2, off);
  }
  __shared__ float red[8];
  const int w = t >> 6;
  if ((t & 63) == 0) { red[w] = s; red[4 + w] = s2; }
  __syncthreads();
  const float ts  = red[0] + red[1] + red[2] + red[3];
  const float ts2 = red[4] + red[5] + red[6] + red[7];
  const float mean = ts * (1.f / D_);
  const float var  = ts2 * (1.f / D_) - mean * mean;
  const float inv  = 1.f / sqrtf(var + EPS_);
  const float2 g  = *reinterpret_cast<const float2*>(gamma + t * 2);
  const float2 bt = *reinterpret_cast<const float2*>(beta + t * 2);
  float2 o;
  o.x = g.x * ((hx - mean) * inv) + bt.x;
  o.y = g.y * ((hy - mean) * inv) + bt.y;
  *reinterpret_cast<float2*>(out + ro) = o;
}

// ---------------------------------------------------------------------------
extern "C" void kernel_launch(void* const* d_in, const int* in_sizes, int n_in,
                              void* d_out, int out_size, void* d_ws, size_t ws_size,
                              hipStream_t stream) {
  const float* x       = (const float*)d_in[0];
  const int*   lengths = (const int*)d_in[1];
  const float* Wq = (const float*)d_in[2];
  const float* bq = (const float*)d_in[3];
  const float* Wk = (const float*)d_in[4];
  const float* bk = (const float*)d_in[5];
  const float* Wv = (const float*)d_in[6];
  const float* bv = (const float*)d_in[7];
  const float* Wo = (const float*)d_in[8];
  const float* bo = (const float*)d_in[9];
  const float* W1 = (const float*)d_in[10];
  const float* b1 = (const float*)d_in[11];
  const float* W2 = (const float*)d_in[12];
  const float* b2 = (const float*)d_in[13];
  const float* gamma1 = (const float*)d_in[14];
  const float* beta1  = (const float*)d_in[15];
  const float* gamma2 = (const float*)d_in[16];
  const float* beta2  = (const float*)d_in[17];
  float* out = (float*)d_out;

  char* ws = (char*)d_ws;
  // ---- workspace layout (lifetime-overlapped, < 64 MB) ----
  bf16*  qkvT_hi = (bf16*)(ws + 0);          // [1536][512]
  bf16*  qkvT_lo = (bf16*)(ws + 1572864);
  bf16*  WoT_hi  = (bf16*)(ws + 3145728);    // [512][512]
  bf16*  WoT_lo  = (bf16*)(ws + 3670016);
  bf16*  W1T_hi  = (bf16*)(ws + 4194304);    // [2048][512]
  bf16*  W1T_lo  = (bf16*)(ws + 6291456);
  bf16*  W2T_hi  = (bf16*)(ws + 8388608);    // [512][2048]
  bf16*  W2T_lo  = (bf16*)(ws + 10485760);
  float* bqkv    = (float*)(ws + 12582912);  // [1536]
  // region A: qk hi/lo + v f32 (24MB) -> Wo partials P0/P1 -> ff1 hi/lo
  bf16*  qk_hi   = (bf16*)(ws + 12589056);   // [4096][1024]
  bf16*  qk_lo   = (bf16*)(ws + 20977664);
  float* v_f32   = (float*)(ws + 29366272);  // [4096][512], ends 37754880
  float* P0      = (float*)(ws + 12589056);  // [4096][512] (qk dead after attn_part)
  float* P1      = (float*)(ws + 20977664);
  float* part_m  = (float*)(ws + 37754880);  // attn partials, 6MB window
  float* part_l  = (float*)(ws + 39852032);
  float* part_d  = (float*)(ws + 41949184);  // ends 44046336
  bf16*  ff1_hi  = (bf16*)(ws + 12589056);   // [4096][2048] (after LN1)
  bf16*  ff1_lo  = (bf16*)(ws + 29366272);   // ends 46143488
  // region B: xm hi/lo -> y1 hi/lo (live through LN2)
  bf16*  xm_hi   = (bf16*)(ws + 46143488);   // [4096][512]
  bf16*  xm_lo   = (bf16*)(ws + 50337792);
  bf16*  y1_hi   = (bf16*)(ws + 46143488);
  bf16*  y1_lo   = (bf16*)(ws + 50337792);
  // region C: wgt hi/lo -> FF2 partial Q0
  bf16*  wgt_hi  = (bf16*)(ws + 54532096);   // [4096][512]
  bf16*  wgt_lo  = (bf16*)(ws + 58726400);   // ends 62920704
  float* Q0      = (float*)(ws + 54532096);  // (after Wo)
  // FF2 partial Q1 over dead qkvT/WoT/W1T weights (after FF1):
  float* Q1      = (float*)(ws + 0);         // [4096][512] = 8.4MB, ends 8388608

  const dim3 blk(256);
  const int M = B_ * S_;  // 4096

  // 1) weight transposes + hi/lo splits
  Trans4Args ta;
  ta.w[0] = Wq; ta.w[1] = Wk; ta.w[2] = Wv; ta.w[3] = Wo;
  ta.thi[0] = qkvT_hi; ta.thi[1] = qkvT_hi; ta.thi[2] = qkvT_hi; ta.thi[3] = WoT_hi;
  ta.tlo[0] = qkvT_lo; ta.tlo[1] = qkvT_lo; ta.tlo[2] = qkvT_lo; ta.tlo[3] = WoT_lo;
  ta.rowOff[0] = 0; ta.rowOff[1] = 512; ta.rowOff[2] = 1024; ta.rowOff[3] = 0;
  transpose4_kernel<<<dim3(16, 16, 4), blk, 0, stream>>>(ta);
  transpose_split_kernel<<<dim3(64, 16), blk, 0, stream>>>(W1, 512, 2048, W1T_hi, W1T_lo);
  transpose_split_kernel<<<dim3(16, 64), blk, 0, stream>>>(W2, 2048, 512, W2T_hi, W2T_lo);
  pack_bias_kernel<<<dim3(6), blk, 0, stream>>>(bq, bk, bv, bqkv);

  // 2) mask + split
  mask_split_kernel<<<dim3((M * D_ / 4) / 256), blk, 0, stream>>>(x, lengths, xm_hi, xm_lo);

  // 3) fused QKV GEMM -> qk hi/lo (bf16) + v (f32).  grid 32x12 = 384
  gemm_kernel<EPI_QKV, false, 128><<<dim3(384), blk, 0, stream>>>(
      xm_hi, xm_lo, qkvT_hi, qkvT_lo, bqkv,
      v_f32, nullptr, qk_hi, qk_lo, 512, QS_, 12, 384, 512);

  // 4) attention: MFMA partials (272 causal pairs x 16 bh) + merge
  attn_part_kernel<<<dim3(272, 16), blk, 0, stream>>>(qk_hi, qk_lo, lengths,
                                                      part_m, part_l, part_d);
  attn_merge_kernel<<<dim3(32, 16), blk, 0, stream>>>(v_f32, lengths, part_m, part_l, part_d,
                                                      wgt_hi, wgt_lo);

  // 5) O-proj split-K=2 partials.  grid 2x32x8 = 512
  gemm_kernel<EPI_PART, false, 64><<<dim3(512), blk, 0, stream>>>(
      wgt_hi, wgt_lo, WoT_hi, WoT_lo, nullptr,
      P0, P1, nullptr, nullptr, 512, D_, 8, 256, 256);

  // 6) LN1 fused (P0+P1+bo+mask(x)) -> y1 hi/lo
  ln1_fused_kernel<<<dim3(M), blk, 0, stream>>>(P0, P1, x, lengths, bo,
                                                gamma1, beta1, y1_hi, y1_lo);

  // 7) FF1 (+bias+relu) -> ff1 hi/lo.  grid 32x16 = 512
  gemm_kernel<EPI_BIAS_RELU, true, 128><<<dim3(512), blk, 0, stream>>>(
      y1_hi, y1_lo, W1T_hi, W1T_lo, b1,
      nullptr, nullptr, ff1_hi, ff1_lo, 512, FF_, 16, 512, 512);

  // 8) FF2 split-K=2 partials.  grid 2x32x8 = 512
  gemm_kernel<EPI_PART, false, 64><<<dim3(512), blk, 0, stream>>>(
      ff1_hi, ff1_lo, W2T_hi, W2T_lo, nullptr,
      Q0, Q1, nullptr, nullptr, FF_, D_, 8, 256, 1024);

  // 9) LN2 fused (Q0+Q1+b2+y1) -> out
  ln2_fused_kernel<<<dim3(M), blk, 0, stream>>>(Q0, Q1, y1_hi, y1_lo, b2,
                                                gamma2, beta2, out);
}

// Round 11
// 260.009 us; speedup vs baseline: 1.1830x; 1.0238x over previous
//
#include <hip/hip_runtime.h>

// Problem constants (match reference file)
#define B_   2
#define S_   2048
#define D_   512
#define H_   8
#define DK_  64
#define FF_  2048
#define EPS_ 1e-3f
#define QS_  1536   // fused QKV output width (q|k|v)

typedef __bf16 bf16;
typedef __bf16 bf16x4 __attribute__((ext_vector_type(4)));
typedef __bf16 bf16x8 __attribute__((ext_vector_type(8)));
typedef float  f32x4  __attribute__((ext_vector_type(4)));

// async global->LDS, 16B per lane, LDS dest = wave-uniform base + lane*16
__device__ __forceinline__ void gload16(const bf16* g, bf16* l) {
  __builtin_amdgcn_global_load_lds(
      (__attribute__((address_space(1))) void*)g,
      (__attribute__((address_space(3))) void*)l, 16, 0, 0);
}

// ---------------------------------------------------------------------------
// Fused prep kernel (1 launch instead of 5): 1D grid, range-decoded.
//  [0,1024)    : transpose+split Wq/Wk/Wv/Wo (512x512 each)
//  [1024,2048) : transpose+split W1 (512x2048 -> [2048][512])
//  [2048,3072) : transpose+split W2 (2048x512 -> [512][2048])
//  [3072,5120) : mask_split (x -> xm hi/lo)
//  [5120,5126) : pack qkv bias
// All sub-tasks independent; all complete before the QKV GEMM (stream order).
// ---------------------------------------------------------------------------
struct PrepArgs {
  const float* w[4];      // Wq, Wk, Wv, Wo
  bf16* thi[4];
  bf16* tlo[4];
  int rowOff[4];
  const float* W1; bf16* W1hi; bf16* W1lo;
  const float* W2; bf16* W2hi; bf16* W2lo;
  const float* x; const int* lengths; bf16* xhi; bf16* xlo;
  const float* bq; const float* bk; const float* bv; float* bqkv;
};

__device__ __forceinline__ void transpose_tile(const float* W, int K, int N,
                                               bf16* Thi, bf16* Tlo,
                                               int n0, int k0, int rowOff,
                                               float (*tl)[33], int t) {
  const int tx = t & 31, ty = t >> 5;  // 32 x 8
#pragma unroll
  for (int r = 0; r < 32; r += 8)
    tl[r + ty][tx] = W[(size_t)(k0 + r + ty) * N + n0 + tx];
  __syncthreads();
#pragma unroll
  for (int r = 0; r < 32; r += 8) {
    const int n = r + ty;
    const float v = tl[tx][n];  // stride-33 -> conflict-free
    const bf16 h = (bf16)v;
    const size_t o = (size_t)(rowOff + n0 + n) * K + k0 + tx;
    Thi[o] = h;
    Tlo[o] = (bf16)(v - (float)h);
  }
}

__global__ __launch_bounds__(256) void prep_kernel(PrepArgs a) {
  __shared__ float tl[32][33];
  const int id = blockIdx.x;
  const int t = threadIdx.x;
  if (id < 1024) {  // 4x 512x512 transpose+split
    const int wsel = id >> 8, rem = id & 255;
    transpose_tile(a.w[wsel], 512, 512, a.thi[wsel], a.tlo[wsel],
                   (rem & 15) * 32, (rem >> 4) * 32, a.rowOff[wsel], tl, t);
  } else if (id < 2048) {  // W1: [512][2048] -> T[2048][512]
    const int rem = id - 1024;
    transpose_tile(a.W1, 512, 2048, a.W1hi, a.W1lo,
                   (rem & 63) * 32, (rem >> 6) * 32, 0, tl, t);
  } else if (id < 3072) {  // W2: [2048][512] -> T[512][2048]
    const int rem = id - 2048;
    transpose_tile(a.W2, 2048, 512, a.W2hi, a.W2lo,
                   (rem & 15) * 32, (rem >> 4) * 32, 0, tl, t);
  } else if (id < 5120) {  // mask_split: one float4 per thread
    const int idx = (id - 3072) * 256 + t;
    const int d4 = D_ / 4;
    const int s = (idx / d4) & (S_ - 1);
    const int b = idx / (d4 * S_);
    float4 v = reinterpret_cast<const float4*>(a.x)[idx];
    if (s >= a.lengths[b]) { v.x = 0.f; v.y = 0.f; v.z = 0.f; v.w = 0.f; }
    const float vv[4] = {v.x, v.y, v.z, v.w};
    bf16x4 h, l;
#pragma unroll
    for (int c = 0; c < 4; ++c) {
      const bf16 hh = (bf16)vv[c];
      h[c] = hh;
      l[c] = (bf16)(vv[c] - (float)hh);
    }
    reinterpret_cast<bf16x4*>(a.xhi)[idx] = h;
    reinterpret_cast<bf16x4*>(a.xlo)[idx] = l;
  } else {  // pack bias
    const int i = (id - 5120) * 256 + t;
    if (i < 1536)
      a.bqkv[i] = (i < 512) ? a.bq[i] : (i < 1024) ? a.bk[i - 512] : a.bv[i - 1024];
  }
}

// ---------------------------------------------------------------------------
// Split-bf16 MFMA GEMM (m97-style): 128 x BN tile, BK=32, 256 thr = 4 waves
// (2x2 -> per-wave 64 x BN/2). global_load_lds width-16 staging into linear
// LDS [row][32]; fragment-read bank distribution is the 8-lanes/bank-quad
// structural floor (1KB/instr / 128B-per-cyc), permutation-invariant.
// 3 MFMA products per acc (hi*hi + hi*lo + lo*hi) ~ fp32 accuracy.
// OPERAND-SWAPPED epilogue: lane holds C[row=mtile+fr][cols ntile+fg*4..+3]
// -> f32x4/bf16x4 vector stores. Split-K: s=1 -> C2 (no bias), LN sums.
// ---------------------------------------------------------------------------
enum { EPI_BIAS_RELU = 2, EPI_PART = 4, EPI_QKV = 5 };

template <int EPI, bool SPLIT, int BN>
__global__ __launch_bounds__(256) void gemm_kernel(
    const bf16* __restrict__ Ahi, const bf16* __restrict__ Alo,
    const bf16* __restrict__ Bhi, const bf16* __restrict__ Blo,
    const float* __restrict__ bias,
    float* __restrict__ C, float* __restrict__ C2,
    bf16* __restrict__ Chi, bf16* __restrict__ Clo,
    int K, int ldc, int nx, int mn, int ksplit) {
  constexpr int NR = BN / 32;  // n-frags per wave
  __shared__ __align__(16) bf16 As[2][128][32];  // [hi/lo][row][k], linear
  __shared__ __align__(16) bf16 Bs[2][BN][32];
  const int t = threadIdx.x;

  const int nwg = gridDim.x;
  const int chunk = nwg >> 3;
  const int virt = (blockIdx.x & 7) * chunk + (blockIdx.x >> 3);
  const int s = virt / mn;
  const int v2 = virt - s * mn;
  const int m0 = (v2 / nx) * 128, n0 = (v2 % nx) * BN;
  const int kb = s * ksplit;

  const int lane = t & 63, wv = t >> 6;
  const int fr = lane & 15, fg = lane >> 4;
  const int wm = (wv >> 1) * 64, wn = (wv & 1) * (BN / 2);
  const int sr = lane >> 2, sslot = lane & 3;  // staging: 16 rows x 4 chunks

  f32x4 acc[4][NR] = {};

  const bf16* gAh = Ahi + (size_t)m0 * K + kb;
  const bf16* gAl = Alo + (size_t)m0 * K + kb;
  const bf16* gBh = Bhi + (size_t)n0 * K + kb;
  const bf16* gBl = Blo + (size_t)n0 * K + kb;

  for (int k0 = 0; k0 < ksplit; k0 += 32) {
    // ---- async staging: per wave-instr 64 lanes x 16B = 16 rows ----
#pragma unroll
    for (int q = 0; q < 2; ++q) {  // A: 32 rows per wave
      const int r = wv * 32 + q * 16 + sr;
      const size_t go = (size_t)r * K + k0 + sslot * 8;
      gload16(gAh + go, &As[0][wv * 32 + q * 16][0]);
      gload16(gAl + go, &As[1][wv * 32 + q * 16][0]);
    }
    if constexpr (BN == 128) {
#pragma unroll
      for (int q = 0; q < 2; ++q) {
        const int r = wv * 32 + q * 16 + sr;
        const size_t go = (size_t)r * K + k0 + sslot * 8;
        gload16(gBh + go, &Bs[0][wv * 32 + q * 16][0]);
        gload16(gBl + go, &Bs[1][wv * 32 + q * 16][0]);
      }
    } else {  // BN == 64: 16 rows per wave
      const int r = wv * 16 + sr;
      const size_t go = (size_t)r * K + k0 + sslot * 8;
      gload16(gBh + go, &Bs[0][wv * 16][0]);
      gload16(gBl + go, &Bs[1][wv * 16][0]);
    }
    __syncthreads();  // compiler inserts vmcnt(0) drain before barrier

    bf16x8 ah[4], al[4], bh[NR], bl[NR];
#pragma unroll
    for (int m = 0; m < 4; ++m) {
      const int r = wm + m * 16 + fr;
      ah[m] = *reinterpret_cast<const bf16x8*>(&As[0][r][fg * 8]);
      al[m] = *reinterpret_cast<const bf16x8*>(&As[1][r][fg * 8]);
    }
#pragma unroll
    for (int n = 0; n < NR; ++n) {
      const int r = wn + n * 16 + fr;
      bh[n] = *reinterpret_cast<const bf16x8*>(&Bs[0][r][fg * 8]);
      bl[n] = *reinterpret_cast<const bf16x8*>(&Bs[1][r][fg * 8]);
    }
    // C^T fragments: mfma(B, A) (operand-swapped)
#pragma unroll
    for (int m = 0; m < 4; ++m)
#pragma unroll
      for (int n = 0; n < NR; ++n) {
        acc[m][n] = __builtin_amdgcn_mfma_f32_16x16x32_bf16(bh[n], ah[m], acc[m][n], 0, 0, 0);
        acc[m][n] = __builtin_amdgcn_mfma_f32_16x16x32_bf16(bl[n], ah[m], acc[m][n], 0, 0, 0);
        acc[m][n] = __builtin_amdgcn_mfma_f32_16x16x32_bf16(bh[n], al[m], acc[m][n], 0, 0, 0);
      }
    __syncthreads();
  }

  float* __restrict__ Cw = (s == 0) ? C : C2;
#pragma unroll
  for (int m = 0; m < 4; ++m) {
    const int row = m0 + wm + m * 16 + fr;
#pragma unroll
    for (int n = 0; n < NR; ++n) {
      const int col = n0 + wn + n * 16 + fg * 4;  // 4 consecutive cols
      f32x4 v = acc[m][n];
      if constexpr (EPI != EPI_PART) {
        const f32x4 b4 = *reinterpret_cast<const f32x4*>(bias + col);
#pragma unroll
        for (int c = 0; c < 4; ++c) v[c] += b4[c];
      }
      if constexpr (EPI == EPI_BIAS_RELU) {
#pragma unroll
        for (int c = 0; c < 4; ++c) v[c] = fmaxf(v[c], 0.f);
      }
      if constexpr (EPI == EPI_QKV) {
        if (col < 1024) {  // q|k -> bf16 hi/lo, stride 1024 (uniform per block)
          bf16x4 h, l;
#pragma unroll
          for (int c = 0; c < 4; ++c) {
            const bf16 hh = (bf16)v[c];
            h[c] = hh;
            l[c] = (bf16)(v[c] - (float)hh);
          }
          *reinterpret_cast<bf16x4*>(&Chi[(size_t)row * 1024 + col]) = h;
          *reinterpret_cast<bf16x4*>(&Clo[(size_t)row * 1024 + col]) = l;
        } else {  // v -> f32, stride 512
          *reinterpret_cast<f32x4*>(&C[(size_t)row * D_ + col - 1024]) = v;
        }
      } else if constexpr (SPLIT) {
        bf16x4 h, l;
#pragma unroll
        for (int c = 0; c < 4; ++c) {
          const bf16 hh = (bf16)v[c];
          h[c] = hh;
          l[c] = (bf16)(v[c] - (float)hh);
        }
        *reinterpret_cast<bf16x4*>(&Chi[(size_t)row * ldc + col]) = h;
        *reinterpret_cast<bf16x4*>(&Clo[(size_t)row * ldc + col]) = l;
      } else {
        *reinterpret_cast<f32x4*>(&Cw[(size_t)row * ldc + col]) = v;
      }
    }
  }
}

// ---------------------------------------------------------------------------
// Attention phase 1 (MFMA): one block per causal (i-tile64, j-chunk128) pair
// x (b,h). S = Qhi*Khi^T + Qhi*Klo^T + Qlo*Khi^T via mfma_16x16x32_bf16.
// D-frag mapping: query = wv*16 + fg*4 + r, key = jf*16 + fr -> softmax
// reduction = shfl_xor over the 16 fr lanes + 4 jf frags.
// ---------------------------------------------------------------------------
__global__ __launch_bounds__(256) void attn_part_kernel(
    const bf16* __restrict__ qk_hi, const bf16* __restrict__ qk_lo,
    const int* __restrict__ lengths,
    float* __restrict__ pm, float* __restrict__ pl, float* __restrict__ pd) {
  __shared__ __align__(16) bf16 Qh[64][72], Ql[64][72];
  __shared__ __align__(16) bf16 Kh[64][72], Kl[64][72];
  const int t = threadIdx.x;
  const int lane = t & 63, wv = t >> 6;
  const int fr = lane & 15, fg = lane >> 4;
  const int bh = blockIdx.y;
  const int bb = bh >> 3, h = bh & 7;

  // unflatten p -> (ib, jc): ib=2a starts at a^2+a, ib=2a+1 starts at (a+1)^2
  const int p = blockIdx.x;
  int a = (int)sqrtf((float)p);
  while ((a + 1) * (a + 1) <= p) ++a;
  while (a * a > p) --a;
  int ib, jc;
  if (p >= a * a + a) { ib = 2 * a;     jc = p - (a * a + a); }
  else                { ib = 2 * a - 1; jc = p - a * a; }

  const int i0 = ib * 64;
  const int len = lengths[bb];
  if (i0 >= len || jc * 128 >= len) return;  // block-uniform: partials unread

  const int sr = t >> 2, sc0 = (t & 3) * 16;  // staging: row, 16-elem segment
  {  // stage Q hi/lo tile
    const size_t gb = (size_t)(bb * S_ + i0 + sr) * 1024 + h * DK_ + sc0;
    *reinterpret_cast<int4*>(&Qh[sr][sc0])     = *reinterpret_cast<const int4*>(qk_hi + gb);
    *reinterpret_cast<int4*>(&Qh[sr][sc0 + 8]) = *reinterpret_cast<const int4*>(qk_hi + gb + 8);
    *reinterpret_cast<int4*>(&Ql[sr][sc0])     = *reinterpret_cast<const int4*>(qk_lo + gb);
    *reinterpret_cast<int4*>(&Ql[sr][sc0 + 8]) = *reinterpret_cast<const int4*>(qk_lo + gb + 8);
  }

  float m_r[4], l_r[4], d_r[4];
#pragma unroll
  for (int r = 0; r < 4; ++r) { m_r[r] = -1e30f; l_r[r] = 0.f; d_r[r] = 0.f; }

  const int jlim = min(i0 + 63, len - 1);
  for (int jt = 0; jt < 2; ++jt) {
    const int j0 = jc * 128 + jt * 64;
    if (j0 > jlim) break;  // uniform
    {  // stage K hi/lo tile
      const size_t gb = (size_t)(bb * S_ + j0 + sr) * 1024 + 512 + h * DK_ + sc0;
      *reinterpret_cast<int4*>(&Kh[sr][sc0])     = *reinterpret_cast<const int4*>(qk_hi + gb);
      *reinterpret_cast<int4*>(&Kh[sr][sc0 + 8]) = *reinterpret_cast<const int4*>(qk_hi + gb + 8);
      *reinterpret_cast<int4*>(&Kl[sr][sc0])     = *reinterpret_cast<const int4*>(qk_lo + gb);
      *reinterpret_cast<int4*>(&Kl[sr][sc0 + 8]) = *reinterpret_cast<const int4*>(qk_lo + gb + 8);
    }
    __syncthreads();

    f32x4 sc[4] = {};
#pragma unroll
    for (int kk = 0; kk < 2; ++kk) {
      const bf16x8 qh = *reinterpret_cast<const bf16x8*>(&Qh[wv * 16 + fr][kk * 32 + fg * 8]);
      const bf16x8 ql = *reinterpret_cast<const bf16x8*>(&Ql[wv * 16 + fr][kk * 32 + fg * 8]);
#pragma unroll
      for (int jf = 0; jf < 4; ++jf) {
        const bf16x8 kh = *reinterpret_cast<const bf16x8*>(&Kh[jf * 16 + fr][kk * 32 + fg * 8]);
        const bf16x8 kl = *reinterpret_cast<const bf16x8*>(&Kl[jf * 16 + fr][kk * 32 + fg * 8]);
        sc[jf] = __builtin_amdgcn_mfma_f32_16x16x32_bf16(qh, kh, sc[jf], 0, 0, 0);
        sc[jf] = __builtin_amdgcn_mfma_f32_16x16x32_bf16(qh, kl, sc[jf], 0, 0, 0);
        sc[jf] = __builtin_amdgcn_mfma_f32_16x16x32_bf16(ql, kh, sc[jf], 0, 0, 0);
      }
    }

    // online softmax row-stats update (state redundant across the 16 fr lanes)
#pragma unroll
    for (int r = 0; r < 4; ++r) {
      const int ig = i0 + wv * 16 + fg * 4 + r;
      float s4[4];
      float mx = -1e30f;
#pragma unroll
      for (int jf = 0; jf < 4; ++jf) {
        const int j = j0 + jf * 16 + fr;
        float v = sc[jf][r];
        if (j > ig || j >= len) v = -1e30f;  // causal + padding mask
        s4[jf] = v;
        mx = fmaxf(mx, v);
      }
#pragma unroll
      for (int off = 1; off < 16; off <<= 1) mx = fmaxf(mx, __shfl_xor(mx, off));
      const float mnew = fmaxf(m_r[r], mx);
      float ps = 0.f, pdg = 0.f;
#pragma unroll
      for (int jf = 0; jf < 4; ++jf) {
        const float e = __expf(s4[jf] - mnew);
        ps += e;
        if (j0 + jf * 16 + fr == ig) pdg = e;  // diagonal numerator
      }
#pragma unroll
      for (int off = 1; off < 16; off <<= 1) {
        ps += __shfl_xor(ps, off);
        pdg += __shfl_xor(pdg, off);
      }
      const float scale = __expf(m_r[r] - mnew);
      l_r[r] = l_r[r] * scale + ps;
      d_r[r] = d_r[r] * scale + pdg;
      m_r[r] = mnew;
    }
    __syncthreads();
  }

  if (fr == 0) {  // one lane per row writes partials
    const size_t base = ((size_t)(bh * 32 + ib) * 16 + jc) * 64;
#pragma unroll
    for (int r = 0; r < 4; ++r) {
      const int row = wv * 16 + fg * 4 + r;
      const float mm = m_r[r];
      const bool ok = mm > -1e29f;  // row saw >=1 valid key in this chunk
      pm[base + row] = mm;
      pl[base + row] = ok ? l_r[r] : 0.f;
      pd[base + row] = ok ? d_r[r] : 0.f;
    }
  }
}

// ---------------------------------------------------------------------------
// Attention phase 2: merge partials per (b,h,i-tile), write wgt=(d/l)*v bf16
// ---------------------------------------------------------------------------
__global__ __launch_bounds__(256) void attn_merge_kernel(
    const float* __restrict__ vsrc, const int* __restrict__ lengths,
    const float* __restrict__ pm, const float* __restrict__ pl,
    const float* __restrict__ pd, bf16* __restrict__ whi, bf16* __restrict__ wlo) {
  __shared__ float msh[4][64], lsh[4][64], dsh[4][64];
  __shared__ float dgs[64];
  const int t = threadIdx.x;
  const int ib = blockIdx.x, bh = blockIdx.y;
  const int bb = bh >> 3, h = bh & 7;
  const int i0 = ib * 64;
  const int len = lengths[bb];

  const int r = t & 63, g = t >> 6;
  float m = -1e30f, l = 0.f, d = 0.f;
  if (i0 < len) {  // else partials unread (poison-safe: dg forced 0 below)
    const int jcmax = min((i0 + 63) >> 7, (len - 1) >> 7);
    const size_t base = ((size_t)(bh * 32 + ib) * 16) * 64 + r;
    for (int jc = g; jc <= jcmax; jc += 4) {
      const size_t idx = base + (size_t)jc * 64;
      const float m2 = pm[idx], l2 = pl[idx], d2 = pd[idx];
      const float mn = fmaxf(m, m2);
      const float e1 = __expf(m - mn), e2 = __expf(m2 - mn);
      l = l * e1 + l2 * e2;
      d = d * e1 + d2 * e2;
      m = mn;
    }
  }
  msh[g][r] = m; lsh[g][r] = l; dsh[g][r] = d;
  __syncthreads();
  if (t < 64) {
    float M = msh[0][t], L = lsh[0][t], Dv = dsh[0][t];
#pragma unroll
    for (int gg = 1; gg < 4; ++gg) {
      const float m2 = msh[gg][t], l2 = lsh[gg][t], d2 = dsh[gg][t];
      const float mn = fmaxf(M, m2);
      const float e1 = __expf(M - mn), e2 = __expf(m2 - mn);
      L = L * e1 + l2 * e2;
      Dv = Dv * e1 + d2 * e2;
      M = mn;
    }
    // valid rows always have the jc=0 partial with l >= 1 -> L >= 1
    dgs[t] = (i0 + t < len) ? Dv / L : 0.f;
  }
  __syncthreads();

  const int rr = t >> 2, q = t & 3;
  const float dg = dgs[rr];
  const size_t obase = (size_t)(bb * S_ + i0 + rr) * D_ + h * DK_;
#pragma unroll
  for (int kk = 0; kk < 4; ++kk) {
    const int col = q * 4 + kk * 16;
    const float4 v4 = *reinterpret_cast<const float4*>(vsrc + obase + col);
    const float vv[4] = {dg * v4.x, dg * v4.y, dg * v4.z, dg * v4.w};
    bf16x4 hh, ll;
#pragma unroll
    for (int c = 0; c < 4; ++c) {
      const bf16 x = (bf16)vv[c];
      hh[c] = x;
      ll[c] = (bf16)(vv[c] - (float)x);
    }
    *reinterpret_cast<bf16x4*>(&whi[obase + col]) = hh;
    *reinterpret_cast<bf16x4*>(&wlo[obase + col]) = ll;
  }
}

// ---------------------------------------------------------------------------
// LN1 fused: h1 = P0 + P1 + bo + mask(x); y1 = LN(h1) written as bf16 hi/lo.
// ---------------------------------------------------------------------------
__global__ __launch_bounds__(256) void ln1_fused_kernel(
    const float* __restrict__ P0, const float* __restrict__ P1,
    const float* __restrict__ x, const int* __restrict__ lengths,
    const float* __restrict__ bo,
    const float* __restrict__ gamma, const float* __restrict__ beta,
    bf16* __restrict__ Yhi, bf16* __restrict__ Ylo) {
  const int row = blockIdx.x;
  const int t = threadIdx.x;
  const int lenb = lengths[row >> 11];
  const bool valid = (row & (S_ - 1)) < lenb;
  const size_t ro = (size_t)row * D_ + t * 2;
  const float2 p0 = *reinterpret_cast<const float2*>(P0 + ro);
  const float2 p1 = *reinterpret_cast<const float2*>(P1 + ro);
  const float2 xv = *reinterpret_cast<const float2*>(x + ro);
  const float2 bv = *reinterpret_cast<const float2*>(bo + t * 2);
  float hx = p0.x + p1.x + bv.x + (valid ? xv.x : 0.f);
  float hy = p0.y + p1.y + bv.y + (valid ? xv.y : 0.f);

  float s = hx + hy, s2 = hx * hx + hy * hy;
#pragma unroll
  for (int off = 1; off < 64; off <<= 1) {
    s += __shfl_xor(s, off);
    s2 += __shfl_xor(s2, off);
  }
  __shared__ float red[8];
  const int w = t >> 6;
  if ((t & 63) == 0) { red[w] = s; red[4 + w] = s2; }
  __syncthreads();
  const float ts  = red[0] + red[1] + red[2] + red[3];
  const float ts2 = red[4] + red[5] + red[6] + red[7];
  const float mean = ts * (1.f / D_);
  const float var  = ts2 * (1.f / D_) - mean * mean;
  const float inv  = 1.f / sqrtf(var + EPS_);
  const float2 g  = *reinterpret_cast<const float2*>(gamma + t * 2);
  const float2 bt = *reinterpret_cast<const float2*>(beta + t * 2);
  const float ox = g.x * ((hx - mean) * inv) + bt.x;
  const float oy = g.y * ((hy - mean) * inv) + bt.y;
  const bf16 ohx = (bf16)ox, ohy = (bf16)oy;
  Yhi[ro] = ohx;  Yhi[ro + 1] = ohy;
  Ylo[ro] = (bf16)(ox - (float)ohx);
  Ylo[ro + 1] = (bf16)(oy - (float)ohy);
}

// ---------------------------------------------------------------------------
// LN2 fused: h2 = Q0 + Q1 + b2 + (y1hi+y1lo); out = LN(h2) f32.
// ---------------------------------------------------------------------------
__global__ __launch_bounds__(256) void ln2_fused_kernel(
    const float* __restrict__ Q0, const float* __restrict__ Q1,
    const bf16* __restrict__ Yhi, const bf16* __restrict__ Ylo,
    const float* __restrict__ b2,
    const float* __restrict__ gamma, const float* __restrict__ beta,
    float* __restrict__ out) {
  const int row = blockIdx.x;
  const int t = threadIdx.x;
  const size_t ro = (size_t)row * D_ + t * 2;
  const float2 q0 = *reinterpret_cast<const float2*>(Q0 + ro);
  const float2 q1 = *reinterpret_cast<const float2*>(Q1 + ro);
  const float2 bv = *reinterpret_cast<const float2*>(b2 + t * 2);
  const float y1x = (float)Yhi[ro] + (float)Ylo[ro];
  const float y1y = (float)Yhi[ro + 1] + (float)Ylo[ro + 1];
  float hx = q0.x + q1.x + bv.x + y1x;
  float hy = q0.y + q1.y + bv.y + y1y;

  float s = hx + hy, s2 = hx * hx + hy * hy;
#pragma unroll
  for (int off = 1; off < 64; off <<= 1) {
    s += __shfl_xor(s, off);
    s2 += __shfl_xor(s2, off);
  }
  __shared__ float red[8];
  const int w = t >> 6;
  if ((t & 63) == 0) { red[w] = s; red[4 + w] = s2; }
  __syncthreads();
  const float ts  = red[0] + red[1] + red[2] + red[3];
  const float ts2 = red[4] + red[5] + red[6] + red[7];
  const float mean = ts * (1.f / D_);
  const float var  = ts2 * (1.f / D_) - mean * mean;
  const float inv  = 1.f / sqrtf(var + EPS_);
  const float2 g  = *reinterpret_cast<const float2*>(gamma + t * 2);
  const float2 bt = *reinterpret_cast<const float2*>(beta + t * 2);
  float2 o;
  o.x = g.x * ((hx - mean) * inv) + bt.x;
  o.y = g.y * ((hy - mean) * inv) + bt.y;
  *reinterpret_cast<float2*>(out + ro) = o;
}

// ---------------------------------------------------------------------------
extern "C" void kernel_launch(void* const* d_in, const int* in_sizes, int n_in,
                              void* d_out, int out_size, void* d_ws, size_t ws_size,
                              hipStream_t stream) {
  const float* x       = (const float*)d_in[0];
  const int*   lengths = (const int*)d_in[1];
  const float* Wq = (const float*)d_in[2];
  const float* bq = (const float*)d_in[3];
  const float* Wk = (const float*)d_in[4];
  const float* bk = (const float*)d_in[5];
  const float* Wv = (const float*)d_in[6];
  const float* bv = (const float*)d_in[7];
  const float* Wo = (const float*)d_in[8];
  const float* bo = (const float*)d_in[9];
  const float* W1 = (const float*)d_in[10];
  const float* b1 = (const float*)d_in[11];
  const float* W2 = (const float*)d_in[12];
  const float* b2 = (const float*)d_in[13];
  const float* gamma1 = (const float*)d_in[14];
  const float* beta1  = (const float*)d_in[15];
  const float* gamma2 = (const float*)d_in[16];
  const float* beta2  = (const float*)d_in[17];
  float* out = (float*)d_out;

  char* ws = (char*)d_ws;
  // ---- workspace layout (lifetime-overlapped, < 64 MB) ----
  bf16*  qkvT_hi = (bf16*)(ws + 0);          // [1536][512]
  bf16*  qkvT_lo = (bf16*)(ws + 1572864);
  bf16*  WoT_hi  = (bf16*)(ws + 3145728);    // [512][512]
  bf16*  WoT_lo  = (bf16*)(ws + 3670016);
  bf16*  W1T_hi  = (bf16*)(ws + 4194304);    // [2048][512]
  bf16*  W1T_lo  = (bf16*)(ws + 6291456);
  bf16*  W2T_hi  = (bf16*)(ws + 8388608);    // [512][2048]
  bf16*  W2T_lo  = (bf16*)(ws + 10485760);
  float* bqkv    = (float*)(ws + 12582912);  // [1536]
  // region A: qk hi/lo + v f32 (24MB) -> Wo partials P0/P1 -> ff1 hi/lo
  bf16*  qk_hi   = (bf16*)(ws + 12589056);   // [4096][1024]
  bf16*  qk_lo   = (bf16*)(ws + 20977664);
  float* v_f32   = (float*)(ws + 29366272);  // [4096][512], ends 37754880
  float* P0      = (float*)(ws + 12589056);  // [4096][512] (qk dead after attn_part)
  float* P1      = (float*)(ws + 20977664);
  float* part_m  = (float*)(ws + 37754880);  // attn partials, 6MB window
  float* part_l  = (float*)(ws + 39852032);
  float* part_d  = (float*)(ws + 41949184);  // ends 44046336
  bf16*  ff1_hi  = (bf16*)(ws + 12589056);   // [4096][2048] (after LN1)
  bf16*  ff1_lo  = (bf16*)(ws + 29366272);   // ends 46143488
  // region B: xm hi/lo -> y1 hi/lo (live through LN2)
  bf16*  xm_hi   = (bf16*)(ws + 46143488);   // [4096][512]
  bf16*  xm_lo   = (bf16*)(ws + 50337792);
  bf16*  y1_hi   = (bf16*)(ws + 46143488);
  bf16*  y1_lo   = (bf16*)(ws + 50337792);
  // region C: wgt hi/lo -> FF2 partial Q0
  bf16*  wgt_hi  = (bf16*)(ws + 54532096);   // [4096][512]
  bf16*  wgt_lo  = (bf16*)(ws + 58726400);   // ends 62920704
  float* Q0      = (float*)(ws + 54532096);  // (after Wo)
  // FF2 partial Q1 over dead qkvT/WoT/W1T weights (after FF1):
  float* Q1      = (float*)(ws + 0);         // [4096][512] = 8.4MB, ends 8388608

  const dim3 blk(256);
  const int M = B_ * S_;  // 4096

  // 1) fused prep: all weight transposes + bias pack + mask/split (1 launch)
  PrepArgs pa;
  pa.w[0] = Wq; pa.w[1] = Wk; pa.w[2] = Wv; pa.w[3] = Wo;
  pa.thi[0] = qkvT_hi; pa.thi[1] = qkvT_hi; pa.thi[2] = qkvT_hi; pa.thi[3] = WoT_hi;
  pa.tlo[0] = qkvT_lo; pa.tlo[1] = qkvT_lo; pa.tlo[2] = qkvT_lo; pa.tlo[3] = WoT_lo;
  pa.rowOff[0] = 0; pa.rowOff[1] = 512; pa.rowOff[2] = 1024; pa.rowOff[3] = 0;
  pa.W1 = W1; pa.W1hi = W1T_hi; pa.W1lo = W1T_lo;
  pa.W2 = W2; pa.W2hi = W2T_hi; pa.W2lo = W2T_lo;
  pa.x = x; pa.lengths = lengths; pa.xhi = xm_hi; pa.xlo = xm_lo;
  pa.bq = bq; pa.bk = bk; pa.bv = bv; pa.bqkv = bqkv;
  prep_kernel<<<dim3(5126), blk, 0, stream>>>(pa);

  // 2) fused QKV GEMM -> qk hi/lo (bf16) + v (f32).  grid 32x24 = 768
  gemm_kernel<EPI_QKV, false, 64><<<dim3(768), blk, 0, stream>>>(
      xm_hi, xm_lo, qkvT_hi, qkvT_lo, bqkv,
      v_f32, nullptr, qk_hi, qk_lo, 512, QS_, 24, 768, 512);

  // 3) attention: MFMA partials (272 causal pairs x 16 bh) + merge
  attn_part_kernel<<<dim3(272, 16), blk, 0, stream>>>(qk_hi, qk_lo, lengths,
                                                      part_m, part_l, part_d);
  attn_merge_kernel<<<dim3(32, 16), blk, 0, stream>>>(v_f32, lengths, part_m, part_l, part_d,
                                                      wgt_hi, wgt_lo);

  // 4) O-proj split-K=2 partials.  grid 2x32x8 = 512
  gemm_kernel<EPI_PART, false, 64><<<dim3(512), blk, 0, stream>>>(
      wgt_hi, wgt_lo, WoT_hi, WoT_lo, nullptr,
      P0, P1, nullptr, nullptr, 512, D_, 8, 256, 256);

  // 5) LN1 fused (P0+P1+bo+mask(x)) -> y1 hi/lo
  ln1_fused_kernel<<<dim3(M), blk, 0, stream>>>(P0, P1, x, lengths, bo,
                                                gamma1, beta1, y1_hi, y1_lo);

  // 6) FF1 (+bias+relu) -> ff1 hi/lo.  grid 32x32 = 1024
  gemm_kernel<EPI_BIAS_RELU, true, 64><<<dim3(1024), blk, 0, stream>>>(
      y1_hi, y1_lo, W1T_hi, W1T_lo, b1,
      nullptr, nullptr, ff1_hi, ff1_lo, 512, FF_, 32, 1024, 512);

  // 7) FF2 split-K=2 partials.  grid 2x32x8 = 512
  gemm_kernel<EPI_PART, false, 64><<<dim3(512), blk, 0, stream>>>(
      ff1_hi, ff1_lo, W2T_hi, W2T_lo, nullptr,
      Q0, Q1, nullptr, nullptr, FF_, D_, 8, 256, 1024);

  // 8) LN2 fused (Q0+Q1+b2+y1) -> out
  ln2_fused_kernel<<<dim3(M), blk, 0, stream>>>(Q0, Q1, y1_hi, y1_lo, b2,
                                                gamma2, beta2, out);
}